// Round 1
// 2617.387 us; speedup vs baseline: 1.2446x; 1.2446x over previous
//
#include <hip/hip_runtime.h>
#include <hip/hip_bf16.h>
#include <math.h>

// ---- problem constants ----
#define DURZ 6
#define DURX 5
#define SEQ 257
#define LZ 1542   // 6*257 zr tokens
#define LX 1285   // 5*257 xa tokens
#define LT 2827   // LZ+LX
#define DM 512
#define NHEADS 8
#define DH 64
#define HIDDEN 2048

typedef __bf16 bf16x8 __attribute__((ext_vector_type(8)));
typedef __bf16 bf16x4 __attribute__((ext_vector_type(4)));
typedef float f32x4 __attribute__((ext_vector_type(4)));

// ---------------- sentinel fill (diagnostic readout channel) ----------------
__global__ void fill_kernel(float* __restrict__ out, int n, float v) {
    int i = blockIdx.x * blockDim.x + threadIdx.x;
    if (i < n) out[i] = v;
}

// ---------------- embed ----------------
__global__ void embed_kernel(const float* __restrict__ z,
                             const float* __restrict__ frames,
                             const int* __restrict__ actions,
                             const float* __restrict__ W_patch,
                             const float* __restrict__ b_patch,
                             const float* __restrict__ registers,
                             const float* __restrict__ pe,
                             const float* __restrict__ action_emb,
                             float* __restrict__ state) {
    int T = blockIdx.x;
    int tid = threadIdx.x;
    bool is_z = T < LZ;
    int T2 = is_z ? T : T - LZ;
    int f = T2 / SEQ, t = T2 % SEQ;
    if (t < 256) {
        const float* src = is_z ? z : frames;
        int hp = t >> 4, wp = t & 15;
        float pv[12];
#pragma unroll
        for (int c = 0; c < 3; c++)
#pragma unroll
            for (int ph = 0; ph < 2; ph++)
#pragma unroll
                for (int pw = 0; pw < 2; pw++)
                    pv[c * 4 + ph * 2 + pw] =
                        src[((f * 3 + c) * 32 + (hp * 2 + ph)) * 32 + (wp * 2 + pw)];
        for (int d = tid; d < DM; d += 256) {
            float acc = b_patch[d];
#pragma unroll
            for (int j = 0; j < 12; j++) acc += pv[j] * W_patch[j * DM + d];
            acc += pe[t * DM + d];
            state[T * DM + d] = acc;
        }
    } else if (is_z) {
        for (int d = tid; d < DM; d += 256) state[T * DM + d] = registers[d];
    } else {
        int a = actions[f];
        for (int d = tid; d < DM; d += 256) state[T * DM + d] = action_emb[a * DM + d];
    }
}

// ---------------- cond vectors ----------------
__global__ void cond_kernel(const int* __restrict__ ts,
                            const float* __restrict__ time_emb,
                            float* __restrict__ condraw,
                            float* __restrict__ condsilu) {
    int idx = blockIdx.x * blockDim.x + threadIdx.x;
    if (idx >= 7 * 512) return;
    int r = idx >> 9;
    int j = idx & 511;
    int tsr = (r < 6) ? ts[r] : 0;
    float x = time_emb[tsr * 512 + j];
    condraw[idx] = x;
    condsilu[idx] = x / (1.0f + expf(-x));
}

// ---------------- params[i][r][c] ----------------
__global__ void params_kernel(const float* __restrict__ condraw,
                              const float* __restrict__ condsilu,
                              const float* __restrict__ W_mod1,
                              const float* __restrict__ b_mod1,
                              const float* __restrict__ W_mod2,
                              const float* __restrict__ b_mod2,
                              const float* __restrict__ W_g1,
                              const float* __restrict__ b_g1,
                              const float* __restrict__ W_g2,
                              const float* __restrict__ b_g2,
                              float* __restrict__ params) {
    int idx = blockIdx.x * blockDim.x + threadIdx.x;
    if (idx >= 6 * 7 * 3072) return;
    int i = idx / 21504;
    int rem = idx % 21504;
    int r = rem / 3072;
    int c = rem % 3072;
    const float* cv;
    const float* W;
    float bias;
    int ldw;
    if (c < 1024) {
        cv = condsilu + r * 512;
        W = W_mod1 + (size_t)i * 512 * 1024 + c; ldw = 1024;
        bias = b_mod1[i * 1024 + c];
    } else if (c < 2048) {
        int cc = c - 1024;
        cv = condsilu + r * 512;
        W = W_mod2 + (size_t)i * 512 * 1024 + cc; ldw = 1024;
        bias = b_mod2[i * 1024 + cc];
    } else if (c < 2560) {
        int cc = c - 2048;
        cv = condraw + r * 512;
        W = W_g1 + (size_t)i * 512 * 512 + cc; ldw = 512;
        bias = b_g1[i * 512 + cc];
    } else {
        int cc = c - 2560;
        cv = condraw + r * 512;
        W = W_g2 + (size_t)i * 512 * 512 + cc; ldw = 512;
        bias = b_g2[i * 512 + cc];
    }
    float acc = bias;
    for (int j = 0; j < 512; j++) acc += cv[j] * W[(size_t)j * ldw];
    params[idx] = acc;
}

// ---------------- LN + AdaLN modulate ------------
__global__ __launch_bounds__(256) void lnmod_kernel(const float* __restrict__ x,
                                                    float* __restrict__ y,
                                                    const float* __restrict__ params,
                                                    int mod_off) {
    int T = blockIdx.x;
    int tid = threadIdx.x;
    int r = (T < LZ) ? (T / SEQ) : 6;
    const float* prow = params + r * 3072 + mod_off;
    const float* xr = x + (size_t)T * DM;
    float v0 = xr[tid], v1 = xr[tid + 256];
    float s_ = v0 + v1, q_ = v0 * v0 + v1 * v1;
#pragma unroll
    for (int off = 32; off; off >>= 1) {
        s_ += __shfl_down(s_, off);
        q_ += __shfl_down(q_, off);
    }
    __shared__ float sh[8];
    int wave = tid >> 6, lane = tid & 63;
    if (lane == 0) { sh[wave] = s_; sh[4 + wave] = q_; }
    __syncthreads();
    float sum = sh[0] + sh[1] + sh[2] + sh[3];
    float sq = sh[4] + sh[5] + sh[6] + sh[7];
    float mu = sum * (1.0f / 512.0f);
    float var = sq * (1.0f / 512.0f) - mu * mu;
    float rstd = rsqrtf(var + 1e-5f);
    int d0 = tid, d1 = tid + 256;
    y[(size_t)T * DM + d0] = (v0 - mu) * rstd * (1.0f + prow[d0]) + prow[512 + d0];
    y[(size_t)T * DM + d1] = (v1 - mu) * rstd * (1.0f + prow[d1]) + prow[512 + d1];
}

// ================= split-precision bf16 MFMA GEMM family =====================
// f32 operands split hi/lo: x = hi + lo, hi=(bf16)x, lo=(bf16)(x-hi).
// A@W ~= Ah@Wh + Ah@Wl + Al@Wh  (3 MFMAs, error ~2^-17 relative).
// 128x128 tile, 4 waves, each 4x4 of 16x16x32. C/D (m89): row=(lane>>4)*4+reg,
// col=lane&15. LDS rows padded to 40 bf16 (80B).

#define SPLIT_STORE(TH, TL, smv, khv, cc, val)              \
    {                                                       \
        float _v = (val);                                   \
        __bf16 _h = (__bf16)_v;                             \
        TH[smv][khv + cc] = _h;                             \
        TL[smv][khv + cc] = (__bf16)(_v - (float)_h);       \
    }

#define MFMA3(accv, ah, al, bh, bl)                                            \
    accv = __builtin_amdgcn_mfma_f32_16x16x32_bf16(al, bh, accv, 0, 0, 0);     \
    accv = __builtin_amdgcn_mfma_f32_16x16x32_bf16(ah, bl, accv, 0, 0, 0);     \
    accv = __builtin_amdgcn_mfma_f32_16x16x32_bf16(ah, bh, accv, 0, 0, 0);

// ---- fused q/k/v projection ------------------------------------------------
__global__ __launch_bounds__(256) void mgemm_qkv(const float* __restrict__ A,
                                                 const float* __restrict__ Wq,
                                                 const float* __restrict__ Wk,
                                                 const float* __restrict__ Wv,
                                                 const float* __restrict__ bq,
                                                 const float* __restrict__ bk,
                                                 const float* __restrict__ bv,
                                                 float* __restrict__ Cq,
                                                 float* __restrict__ Ck,
                                                 float* __restrict__ Cv, int M) {
    __shared__ __align__(16) __bf16 Ah[128][40], Al[128][40];
    __shared__ __align__(16) __bf16 Bh[128][40], Bl[128][40];
    const int K = 512, N = 512;
    int tid = threadIdx.x;
    int sel = blockIdx.x >> 2;
    int n0 = (blockIdx.x & 3) * 128;
    int m0 = blockIdx.y * 128;
    const float* W = sel == 0 ? Wq : (sel == 1 ? Wk : Wv);
    const float* bias = sel == 0 ? bq : (sel == 1 ? bk : bv);
    float* C = sel == 0 ? Cq : (sel == 1 ? Ck : Cv);
    int w = tid >> 6, lane = tid & 63;
    int wm = (w >> 1) * 64, wn = (w & 1) * 64;
    int q = lane >> 4, lr = lane & 15;
    int sm = tid & 127, kh = (tid >> 7) * 16;
    bool mval = (m0 + sm) < M;
    f32x4 acc[4][4];
#pragma unroll
    for (int i = 0; i < 4; ++i)
#pragma unroll
        for (int j = 0; j < 4; ++j)
#pragma unroll
            for (int r = 0; r < 4; ++r) acc[i][j][r] = 0.0f;
    for (int k0 = 0; k0 < K; k0 += 32) {
        float av[16], wv[16];
        const float* ap = A + (size_t)(m0 + sm) * K + k0 + kh;
#pragma unroll
        for (int c = 0; c < 4; ++c) {
            float4 t = mval ? *(const float4*)(ap + c * 4) : make_float4(0, 0, 0, 0);
            av[c * 4 + 0] = t.x; av[c * 4 + 1] = t.y;
            av[c * 4 + 2] = t.z; av[c * 4 + 3] = t.w;
        }
#pragma unroll
        for (int c = 0; c < 16; ++c)
            wv[c] = W[(size_t)(k0 + kh + c) * N + n0 + sm];
        __syncthreads();
#pragma unroll
        for (int c = 0; c < 16; ++c) {
            SPLIT_STORE(Ah, Al, sm, kh, c, av[c]);
            SPLIT_STORE(Bh, Bl, sm, kh, c, wv[c]);
        }
        __syncthreads();
        bf16x8 afh[4], afl[4], bfh[4], bfl[4];
#pragma unroll
        for (int i = 0; i < 4; ++i) {
            afh[i] = *(const bf16x8*)(&Ah[wm + i * 16 + lr][q * 8]);
            afl[i] = *(const bf16x8*)(&Al[wm + i * 16 + lr][q * 8]);
        }
#pragma unroll
        for (int j = 0; j < 4; ++j) {
            bfh[j] = *(const bf16x8*)(&Bh[wn + j * 16 + lr][q * 8]);
            bfl[j] = *(const bf16x8*)(&Bl[wn + j * 16 + lr][q * 8]);
        }
#pragma unroll
        for (int i = 0; i < 4; ++i)
#pragma unroll
            for (int j = 0; j < 4; ++j) {
                MFMA3(acc[i][j], afh[i], afl[i], bfh[j], bfl[j]);
            }
    }
#pragma unroll
    for (int i = 0; i < 4; ++i)
#pragma unroll
        for (int r = 0; r < 4; ++r) {
            int m = m0 + wm + i * 16 + q * 4 + r;
            if (m < M) {
#pragma unroll
                for (int j = 0; j < 4; ++j) {
                    int n = n0 + wn + j * 16 + lr;
                    C[(size_t)m * N + n] = acc[i][j][r] + bias[n];
                }
            }
        }
}

// ---- generic 512x512 projection (o-proj) -----------------------------------
__global__ __launch_bounds__(256) void mgemm_bias(const float* __restrict__ A,
                                                  const float* __restrict__ W,
                                                  const float* __restrict__ bias,
                                                  float* __restrict__ C, int M) {
    __shared__ __align__(16) __bf16 Ah[128][40], Al[128][40];
    __shared__ __align__(16) __bf16 Bh[128][40], Bl[128][40];
    const int K = 512, N = 512;
    int tid = threadIdx.x;
    int n0 = blockIdx.x * 128;
    int m0 = blockIdx.y * 128;
    int w = tid >> 6, lane = tid & 63;
    int wm = (w >> 1) * 64, wn = (w & 1) * 64;
    int q = lane >> 4, lr = lane & 15;
    int sm = tid & 127, kh = (tid >> 7) * 16;
    bool mval = (m0 + sm) < M;
    f32x4 acc[4][4];
#pragma unroll
    for (int i = 0; i < 4; ++i)
#pragma unroll
        for (int j = 0; j < 4; ++j)
#pragma unroll
            for (int r = 0; r < 4; ++r) acc[i][j][r] = 0.0f;
    for (int k0 = 0; k0 < K; k0 += 32) {
        float av[16], wv[16];
        const float* ap = A + (size_t)(m0 + sm) * K + k0 + kh;
#pragma unroll
        for (int c = 0; c < 4; ++c) {
            float4 t = mval ? *(const float4*)(ap + c * 4) : make_float4(0, 0, 0, 0);
            av[c * 4 + 0] = t.x; av[c * 4 + 1] = t.y;
            av[c * 4 + 2] = t.z; av[c * 4 + 3] = t.w;
        }
#pragma unroll
        for (int c = 0; c < 16; ++c)
            wv[c] = W[(size_t)(k0 + kh + c) * N + n0 + sm];
        __syncthreads();
#pragma unroll
        for (int c = 0; c < 16; ++c) {
            SPLIT_STORE(Ah, Al, sm, kh, c, av[c]);
            SPLIT_STORE(Bh, Bl, sm, kh, c, wv[c]);
        }
        __syncthreads();
        bf16x8 afh[4], afl[4], bfh[4], bfl[4];
#pragma unroll
        for (int i = 0; i < 4; ++i) {
            afh[i] = *(const bf16x8*)(&Ah[wm + i * 16 + lr][q * 8]);
            afl[i] = *(const bf16x8*)(&Al[wm + i * 16 + lr][q * 8]);
        }
#pragma unroll
        for (int j = 0; j < 4; ++j) {
            bfh[j] = *(const bf16x8*)(&Bh[wn + j * 16 + lr][q * 8]);
            bfl[j] = *(const bf16x8*)(&Bl[wn + j * 16 + lr][q * 8]);
        }
#pragma unroll
        for (int i = 0; i < 4; ++i)
#pragma unroll
            for (int j = 0; j < 4; ++j) {
                MFMA3(acc[i][j], afh[i], afl[i], bfh[j], bfl[j]);
            }
    }
#pragma unroll
    for (int i = 0; i < 4; ++i)
#pragma unroll
        for (int r = 0; r < 4; ++r) {
            int m = m0 + wm + i * 16 + q * 4 + r;
            if (m < M) {
#pragma unroll
                for (int j = 0; j < 4; ++j) {
                    int n = n0 + wn + j * 16 + lr;
                    C[(size_t)m * N + n] = acc[i][j][r] + bias[n];
                }
            }
        }
}

// ---- GEGLU: h[m][n] = (A@Wa+ba)*gelu(A@Wg+bg), h f32 [M x 2048] ------------
__global__ __launch_bounds__(256) void mgemm_geglu(const float* __restrict__ A,
                                                   const float* __restrict__ W,
                                                   const float* __restrict__ bias,
                                                   float* __restrict__ H, int M) {
    __shared__ __align__(16) __bf16 Ah[128][40], Al[128][40];
    __shared__ __align__(16) __bf16 Bah[128][40], Bal[128][40];
    __shared__ __align__(16) __bf16 Bgh[128][40], Bgl[128][40];
    const int K = 512, NW = 4096;
    int tid = threadIdx.x;
    int n0 = blockIdx.x * 128;
    int m0 = blockIdx.y * 128;
    int w = tid >> 6, lane = tid & 63;
    int wm = (w >> 1) * 64, wn = (w & 1) * 64;
    int q = lane >> 4, lr = lane & 15;
    int sm = tid & 127, kh = (tid >> 7) * 16;
    bool mval = (m0 + sm) < M;
    f32x4 acca[4][4], accg[4][4];
#pragma unroll
    for (int i = 0; i < 4; ++i)
#pragma unroll
        for (int j = 0; j < 4; ++j)
#pragma unroll
            for (int r = 0; r < 4; ++r) { acca[i][j][r] = 0.0f; accg[i][j][r] = 0.0f; }
    for (int k0 = 0; k0 < K; k0 += 32) {
        float av[16], wa[16], wg[16];
        const float* ap = A + (size_t)(m0 + sm) * K + k0 + kh;
#pragma unroll
        for (int c = 0; c < 4; ++c) {
            float4 t = mval ? *(const float4*)(ap + c * 4) : make_float4(0, 0, 0, 0);
            av[c * 4 + 0] = t.x; av[c * 4 + 1] = t.y;
            av[c * 4 + 2] = t.z; av[c * 4 + 3] = t.w;
        }
#pragma unroll
        for (int c = 0; c < 16; ++c) {
            size_t ro = (size_t)(k0 + kh + c) * NW + n0 + sm;
            wa[c] = W[ro];
            wg[c] = W[ro + 2048];
        }
        __syncthreads();
#pragma unroll
        for (int c = 0; c < 16; ++c) {
            SPLIT_STORE(Ah, Al, sm, kh, c, av[c]);
            SPLIT_STORE(Bah, Bal, sm, kh, c, wa[c]);
            SPLIT_STORE(Bgh, Bgl, sm, kh, c, wg[c]);
        }
        __syncthreads();
        bf16x8 afh[4], afl[4];
#pragma unroll
        for (int i = 0; i < 4; ++i) {
            afh[i] = *(const bf16x8*)(&Ah[wm + i * 16 + lr][q * 8]);
            afl[i] = *(const bf16x8*)(&Al[wm + i * 16 + lr][q * 8]);
        }
#pragma unroll
        for (int j = 0; j < 4; ++j) {
            bf16x8 bah = *(const bf16x8*)(&Bah[wn + j * 16 + lr][q * 8]);
            bf16x8 bal = *(const bf16x8*)(&Bal[wn + j * 16 + lr][q * 8]);
            bf16x8 bgh = *(const bf16x8*)(&Bgh[wn + j * 16 + lr][q * 8]);
            bf16x8 bgl = *(const bf16x8*)(&Bgl[wn + j * 16 + lr][q * 8]);
#pragma unroll
            for (int i = 0; i < 4; ++i) {
                MFMA3(acca[i][j], afh[i], afl[i], bah, bal);
                MFMA3(accg[i][j], afh[i], afl[i], bgh, bgl);
            }
        }
    }
#pragma unroll
    for (int i = 0; i < 4; ++i)
#pragma unroll
        for (int r = 0; r < 4; ++r) {
            int m = m0 + wm + i * 16 + q * 4 + r;
            if (m < M) {
#pragma unroll
                for (int j = 0; j < 4; ++j) {
                    int n = n0 + wn + j * 16 + lr;
                    float a = acca[i][j][r] + bias[n];
                    float g = accg[i][j][r] + bias[2048 + n];
                    float gel = 0.5f * g * (1.0f + erff(g * 0.70710678118654752f));
                    H[(size_t)m * HIDDEN + n] = a * gel;
                }
            }
        }
}

// ---- FFN out: C = H(f32, K=2048) @ W + bias --------------------------------
__global__ __launch_bounds__(256) void mgemm_ffout(const float* __restrict__ H,
                                                   const float* __restrict__ W,
                                                   const float* __restrict__ bias,
                                                   float* __restrict__ C, int M) {
    __shared__ __align__(16) __bf16 Ah[128][40], Al[128][40];
    __shared__ __align__(16) __bf16 Bh[128][40], Bl[128][40];
    const int K = 2048, N = 512;
    int tid = threadIdx.x;
    int n0 = blockIdx.x * 128;
    int m0 = blockIdx.y * 128;
    int w = tid >> 6, lane = tid & 63;
    int wm = (w >> 1) * 64, wn = (w & 1) * 64;
    int q = lane >> 4, lr = lane & 15;
    int sm = tid & 127, kh = (tid >> 7) * 16;
    bool mval = (m0 + sm) < M;
    f32x4 acc[4][4];
#pragma unroll
    for (int i = 0; i < 4; ++i)
#pragma unroll
        for (int j = 0; j < 4; ++j)
#pragma unroll
            for (int r = 0; r < 4; ++r) acc[i][j][r] = 0.0f;
    for (int k0 = 0; k0 < K; k0 += 32) {
        float av[16], wv[16];
        const float* ap = H + (size_t)(m0 + sm) * K + k0 + kh;
#pragma unroll
        for (int c = 0; c < 4; ++c) {
            float4 t = mval ? *(const float4*)(ap + c * 4) : make_float4(0, 0, 0, 0);
            av[c * 4 + 0] = t.x; av[c * 4 + 1] = t.y;
            av[c * 4 + 2] = t.z; av[c * 4 + 3] = t.w;
        }
#pragma unroll
        for (int c = 0; c < 16; ++c)
            wv[c] = W[(size_t)(k0 + kh + c) * N + n0 + sm];
        __syncthreads();
#pragma unroll
        for (int c = 0; c < 16; ++c) {
            SPLIT_STORE(Ah, Al, sm, kh, c, av[c]);
            SPLIT_STORE(Bh, Bl, sm, kh, c, wv[c]);
        }
        __syncthreads();
        bf16x8 afh[4], afl[4], bfh[4], bfl[4];
#pragma unroll
        for (int i = 0; i < 4; ++i) {
            afh[i] = *(const bf16x8*)(&Ah[wm + i * 16 + lr][q * 8]);
            afl[i] = *(const bf16x8*)(&Al[wm + i * 16 + lr][q * 8]);
        }
#pragma unroll
        for (int j = 0; j < 4; ++j) {
            bfh[j] = *(const bf16x8*)(&Bh[wn + j * 16 + lr][q * 8]);
            bfl[j] = *(const bf16x8*)(&Bl[wn + j * 16 + lr][q * 8]);
        }
#pragma unroll
        for (int i = 0; i < 4; ++i)
#pragma unroll
            for (int j = 0; j < 4; ++j) {
                MFMA3(acc[i][j], afh[i], afl[i], bfh[j], bfl[j]);
            }
    }
#pragma unroll
    for (int i = 0; i < 4; ++i)
#pragma unroll
        for (int r = 0; r < 4; ++r) {
            int m = m0 + wm + i * 16 + q * 4 + r;
            if (m < M) {
#pragma unroll
                for (int j = 0; j < 4; ++j) {
                    int n = n0 + wn + j * 16 + lr;
                    C[(size_t)m * N + n] = acc[i][j][r] + bias[n];
                }
            }
        }
}

// ---- flash attention: split-precision bf16 MFMA ----------------------------
// S^T = mfma(A=K, B=Q): A-frag row k=sub*16+(lane&15), kd d=(lane>>4)*8+j (both
// contiguous-in-d from natural [row][d] layout — same frag pattern verified by
// mgemm_*). C-layout (m89): col=lane&15 = q, row=(lane>>4)*4+r = k -> each lane
// holds one q column with 4 consecutive k per subtile: softmax reduce = 16 local
// + shfl_xor(16,32); P write = contiguous b64 directly in PV A-layout P[q][k].
// V staged transposed Vt[d][k] (B-frag for PV wants kd=k contiguous at fixed dh).
// Rows padded to 72 bf16 (144B, 16B-aligned) -> b128 frag reads at bank floor.
__global__ __launch_bounds__(256) void fattn_kernel(const float* __restrict__ Q,
                                                    const float* __restrict__ K,
                                                    const float* __restrict__ V,
                                                    float* __restrict__ O) {
    __shared__ __align__(16) __bf16 Kh[64][72], Kl[64][72];
    __shared__ __align__(16) __bf16 Vth[64][72], Vtl[64][72];
    __shared__ __align__(16) __bf16 Ph[4][16][72], Pl[4][16][72];
    int tid = threadIdx.x;
    int w = tid >> 6, lane = tid & 63;
    int lq = lane & 15, lg = lane >> 4;
    int hoff = blockIdx.z * DH;
    int qbase, base0, len0, base1, len1;
    if (blockIdx.y < 6) {
        int f = blockIdx.y;
        qbase = f * SEQ;
        base0 = f * SEQ; len0 = SEQ;
        int jl = f - 4; if (jl < 0) jl = 0;
        base1 = LZ + jl * SEQ; len1 = (f - jl) * SEQ;
    } else {
        int f = blockIdx.y - 6;
        qbase = LZ + f * SEQ;
        base0 = LZ; len0 = (f + 1) * SEQ;
        base1 = 0; len1 = 0;
    }
    int q0 = blockIdx.x * 64;
    int qvalid = SEQ - q0; if (qvalid > 64) qvalid = 64;

    // per-wave Q B-fragments: col q = w*16+lq, d = s*32 + lg*8 + j
    bf16x8 qh[2], ql[2];
    {
        int qr = w * 16 + lq;
        bool v = qr < qvalid;
        const float* qp = Q + (size_t)(qbase + q0 + qr) * DM + hoff + lg * 8;
#pragma unroll
        for (int s = 0; s < 2; ++s) {
            float4 a = v ? *(const float4*)(qp + s * 32) : make_float4(0, 0, 0, 0);
            float4 b = v ? *(const float4*)(qp + s * 32 + 4) : make_float4(0, 0, 0, 0);
            float fa[8] = {a.x, a.y, a.z, a.w, b.x, b.y, b.z, b.w};
#pragma unroll
            for (int j = 0; j < 8; ++j) {
                __bf16 hh = (__bf16)fa[j];
                qh[s][j] = hh;
                ql[s][j] = (__bf16)(fa[j] - (float)hh);
            }
        }
    }
    f32x4 acc[4];
#pragma unroll
    for (int n = 0; n < 4; ++n)
#pragma unroll
        for (int r = 0; r < 4; ++r) acc[n][r] = 0.0f;
    float m_i = -1e30f, l_i = 0.0f;

    for (int rng = 0; rng < 2; ++rng) {
        int base = rng ? base1 : base0;
        int len = rng ? len1 : len0;
        for (int t0 = 0; t0 < len; t0 += 64) {
            int valid = len - t0; if (valid > 64) valid = 64;
            __syncthreads();
            // ---- stage K [k][d], split hi/lo ----
            {
                int kr = tid >> 2, kc = (tid & 3) * 16;
                const float* kp = K + (size_t)(base + t0 + kr) * DM + hoff + kc;
                bool v = kr < valid;
                bf16x8 h0, h1, l0, l1;
#pragma unroll
                for (int c = 0; c < 4; ++c) {
                    float4 t4 = v ? *(const float4*)(kp + c * 4) : make_float4(0, 0, 0, 0);
                    float f4a[4] = {t4.x, t4.y, t4.z, t4.w};
#pragma unroll
                    for (int j = 0; j < 4; ++j) {
                        int idx = c * 4 + j;
                        __bf16 hh = (__bf16)f4a[j];
                        __bf16 ll = (__bf16)(f4a[j] - (float)hh);
                        if (idx < 8) { h0[idx] = hh; l0[idx] = ll; }
                        else { h1[idx - 8] = hh; l1[idx - 8] = ll; }
                    }
                }
                *(bf16x8*)&Kh[kr][kc] = h0;
                *(bf16x8*)&Kh[kr][kc + 8] = h1;
                *(bf16x8*)&Kl[kr][kc] = l0;
                *(bf16x8*)&Kl[kr][kc + 8] = l1;
            }
            // ---- stage V transposed Vt[d][k], split hi/lo ----
            {
                int d = tid & 63, kq = (tid >> 6) * 16;
                bf16x8 h0, h1, l0, l1;
#pragma unroll
                for (int j = 0; j < 16; ++j) {
                    float x = (kq + j < valid)
                        ? V[(size_t)(base + t0 + kq + j) * DM + hoff + d] : 0.0f;
                    __bf16 hh = (__bf16)x;
                    __bf16 ll = (__bf16)(x - (float)hh);
                    if (j < 8) { h0[j] = hh; l0[j] = ll; }
                    else { h1[j - 8] = hh; l1[j - 8] = ll; }
                }
                *(bf16x8*)&Vth[d][kq] = h0;
                *(bf16x8*)&Vth[d][kq + 8] = h1;
                *(bf16x8*)&Vtl[d][kq] = l0;
                *(bf16x8*)&Vtl[d][kq + 8] = l1;
            }
            __syncthreads();
            // ---- S^T: 4 k-subtiles, dh=64 -> 2 kd steps each ----
            f32x4 st[4];
#pragma unroll
            for (int sub = 0; sub < 4; ++sub)
#pragma unroll
                for (int r = 0; r < 4; ++r) st[sub][r] = 0.0f;
#pragma unroll
            for (int sub = 0; sub < 4; ++sub) {
#pragma unroll
                for (int s = 0; s < 2; ++s) {
                    bf16x8 kfh = *(const bf16x8*)(&Kh[sub * 16 + lq][s * 32 + lg * 8]);
                    bf16x8 kfl = *(const bf16x8*)(&Kl[sub * 16 + lq][s * 32 + lg * 8]);
                    MFMA3(st[sub], kfh, kfl, qh[s], ql[s]);
                }
            }
            // ---- online softmax over k (fixed q = lq per lane) ----
            float p[16];
            float rmax = -1e30f;
#pragma unroll
            for (int sub = 0; sub < 4; ++sub)
#pragma unroll
                for (int r = 0; r < 4; ++r) {
                    int kk = sub * 16 + lg * 4 + r;
                    float sv = (kk < valid) ? st[sub][r] * 0.125f : -1e30f;
                    p[sub * 4 + r] = sv;
                    rmax = fmaxf(rmax, sv);
                }
            rmax = fmaxf(rmax, __shfl_xor(rmax, 16));
            rmax = fmaxf(rmax, __shfl_xor(rmax, 32));
            float mnew = fmaxf(m_i, rmax);
            float alpha = __expf(m_i - mnew);
            float rsum = 0.0f;
#pragma unroll
            for (int i2 = 0; i2 < 16; ++i2) {
                p[i2] = __expf(p[i2] - mnew);
                rsum += p[i2];
            }
            rsum += __shfl_xor(rsum, 16);
            rsum += __shfl_xor(rsum, 32);
            l_i = l_i * alpha + rsum;
            m_i = mnew;
            // rescale acc rows: acc row q = lg*4 + r; alpha for q' held by lane q'
            float ar[4];
#pragma unroll
            for (int r = 0; r < 4; ++r) ar[r] = __shfl(alpha, lg * 4 + r);
#pragma unroll
            for (int n = 0; n < 4; ++n)
#pragma unroll
                for (int r = 0; r < 4; ++r) acc[n][r] *= ar[r];
            // ---- P -> wave-private LDS in PV A-layout P[q][k] ----
#pragma unroll
            for (int sub = 0; sub < 4; ++sub) {
                bf16x4 h4, l4;
#pragma unroll
                for (int r = 0; r < 4; ++r) {
                    float x = p[sub * 4 + r];
                    __bf16 hh = (__bf16)x;
                    h4[r] = hh;
                    l4[r] = (__bf16)(x - (float)hh);
                }
                *(bf16x4*)&Ph[w][lq][sub * 16 + lg * 4] = h4;
                *(bf16x4*)&Pl[w][lq][sub * 16 + lg * 4] = l4;
            }
            bf16x8 pah[2], pal[2];
#pragma unroll
            for (int s = 0; s < 2; ++s) {
                pah[s] = *(const bf16x8*)(&Ph[w][lq][s * 32 + lg * 8]);
                pal[s] = *(const bf16x8*)(&Pl[w][lq][s * 32 + lg * 8]);
            }
            // ---- PV: acc[n] += P @ V ----
#pragma unroll
            for (int n = 0; n < 4; ++n) {
#pragma unroll
                for (int s = 0; s < 2; ++s) {
                    bf16x8 vfh = *(const bf16x8*)(&Vth[n * 16 + lq][s * 32 + lg * 8]);
                    bf16x8 vfl = *(const bf16x8*)(&Vtl[n * 16 + lq][s * 32 + lg * 8]);
                    MFMA3(acc[n], pah[s], pal[s], vfh, vfl);
                }
            }
        }
    }
    float linv[4];
#pragma unroll
    for (int r = 0; r < 4; ++r) linv[r] = 1.0f / __shfl(l_i, lg * 4 + r);
#pragma unroll
    for (int r = 0; r < 4; ++r) {
        int qr = w * 16 + lg * 4 + r;
        if (qr < qvalid) {
            float* op = O + (size_t)(qbase + q0 + qr) * DM + hoff;
#pragma unroll
            for (int n = 0; n < 4; ++n) op[n * 16 + lq] = acc[n][r] * linv[r];
        }
    }
}

// ---------------- gate1 + residual add ----------------
__global__ void gate1add_kernel(const float* __restrict__ xn,
                                const float* __restrict__ proj,
                                float* __restrict__ y2,
                                const float* __restrict__ params) {
    int idx = blockIdx.x * blockDim.x + threadIdx.x;
    if (idx >= LT * DM) return;
    int T = idx >> 9, d = idx & 511;
    int r = (T < LZ) ? (T / SEQ) : 6;
    y2[idx] = xn[idx] * params[r * 3072 + 2048 + d] + proj[idx];
}

// ---------------- gate2 ----------------
__global__ void gate2_kernel(const float* __restrict__ src, float* __restrict__ state,
                             const float* __restrict__ params) {
    int idx = blockIdx.x * blockDim.x + threadIdx.x;
    if (idx >= LT * DM) return;
    int T = idx >> 9, d = idx & 511;
    int r = (T < LZ) ? (T / SEQ) : 6;
    state[idx] = src[idx] * params[r * 3072 + 2560 + d];
}

// ---------------- unpatch to FP32 output ------------------
__global__ void unpatch_kernel(const float* __restrict__ state,
                               const float* __restrict__ Wu,
                               const float* __restrict__ bu,
                               float* __restrict__ out) {
    int idx = blockIdx.x * blockDim.x + threadIdx.x;
    if (idx >= DURZ * 3 * 32 * 32) return;
    int w = idx & 31, hh = (idx >> 5) & 31, c = (idx >> 10) % 3, f = idx / (3 * 1024);
    int t = (hh >> 1) * 16 + (w >> 1);
    int j = c * 4 + (hh & 1) * 2 + (w & 1);
    const float* xr = state + (size_t)(f * SEQ + t) * DM;
    float acc = bu[j];
    for (int k = 0; k < DM; ++k) acc += xr[k] * Wu[k * 12 + j];
    out[idx] = acc;
}

extern "C" void kernel_launch(void* const* d_in, const int* in_sizes, int n_in,
                              void* d_out, int out_size, void* d_ws, size_t ws_size,
                              hipStream_t stream) {
    static const int expected_sizes[32] = {
        18432, 15360, 6, 6,
        6144, 512, 6144, 12,
        512, 131072, 1536, 512000,
        3145728, 6144, 3145728, 6144,
        1572864, 3072, 1572864, 3072,
        1572864, 3072, 1572864, 3072,
        1572864, 3072, 1572864, 3072,
        12582912, 24576, 6291456, 3072
    };
    if (n_in != 32) {
        fill_kernel<<<(18432 + 255) / 256, 256, 0, stream>>>((float*)d_out, 18432, 3.0f);
        return;
    }
    for (int i = 0; i < 32; ++i) {
        if (in_sizes[i] != expected_sizes[i]) {
            fill_kernel<<<(18432 + 255) / 256, 256, 0, stream>>>((float*)d_out, 18432,
                                                                 4.0f + (float)i);
            return;
        }
    }

    const float* z = (const float*)d_in[0];
    const float* frames = (const float*)d_in[1];
    const int* actions = (const int*)d_in[2];
    const int* ts = (const int*)d_in[3];
    const float* W_patch = (const float*)d_in[4];
    const float* b_patch = (const float*)d_in[5];
    const float* W_unpatch = (const float*)d_in[6];
    const float* b_unpatch = (const float*)d_in[7];
    const float* registers = (const float*)d_in[8];
    const float* pe_grid = (const float*)d_in[9];
    const float* action_emb = (const float*)d_in[10];
    const float* time_emb = (const float*)d_in[11];
    const float* W_mod1 = (const float*)d_in[12];
    const float* b_mod1 = (const float*)d_in[13];
    const float* W_mod2 = (const float*)d_in[14];
    const float* b_mod2 = (const float*)d_in[15];
    const float* W_q = (const float*)d_in[16];
    const float* b_q = (const float*)d_in[17];
    const float* W_k = (const float*)d_in[18];
    const float* b_k = (const float*)d_in[19];
    const float* W_v = (const float*)d_in[20];
    const float* b_v = (const float*)d_in[21];
    const float* W_o = (const float*)d_in[22];
    const float* b_o = (const float*)d_in[23];
    const float* W_g1 = (const float*)d_in[24];
    const float* b_g1 = (const float*)d_in[25];
    const float* W_g2 = (const float*)d_in[26];
    const float* b_g2 = (const float*)d_in[27];
    const float* W_geglu = (const float*)d_in[28];
    const float* b_geglu = (const float*)d_in[29];
    const float* W_ffout = (const float*)d_in[30];
    const float* b_ffout = (const float*)d_in[31];

    const size_t S = (size_t)LT * DM;  // 1,447,424
    size_t need = (8 * S + 129024 + 7168) * sizeof(float);
    if (ws_size < need) {
        fill_kernel<<<(18432 + 255) / 256, 256, 0, stream>>>((float*)d_out, 18432, 40.0f);
        return;
    }
    float* ws = (float*)d_ws;
    float* state = ws;
    float* xn = ws + S;
    float* qb = ws + 2 * S;
    float* kb = ws + 3 * S;
    float* vb = ws + 4 * S;
    float* attno = ws + 5 * S;      // reused as y2 after o-proj
    float* proj = ws + 6 * S;
    float* params = ws + 8 * S;
    float* condraw = params + 129024;
    float* condsilu = condraw + 3584;
    float* hbuf = qb;               // LT x 2048 f32 = 4S region (q/k/v/attno dead)

    embed_kernel<<<LT, 256, 0, stream>>>(z, frames, actions, W_patch, b_patch,
                                         registers, pe_grid, action_emb, state);
    cond_kernel<<<(7 * 512 + 255) / 256, 256, 0, stream>>>(ts, time_emb, condraw, condsilu);
    params_kernel<<<(6 * 7 * 3072 + 255) / 256, 256, 0, stream>>>(
        condraw, condsilu, W_mod1, b_mod1, W_mod2, b_mod2, W_g1, b_g1, W_g2, b_g2, params);

    const int MT = (LT + 127) / 128;  // 23
    dim3 gqkv(12, MT);
    dim3 g1(4, MT);
    dim3 gglu(16, MT);
    dim3 gattn(5, 11, NHEADS);
    int ew = (LT * DM + 255) / 256;
    for (int i = 0; i < 6; ++i) {
        const float* P = params + i * 21504;
        lnmod_kernel<<<LT, 256, 0, stream>>>(state, xn, P, 0);
        mgemm_qkv<<<gqkv, 256, 0, stream>>>(xn,
            W_q + (size_t)i * DM * DM, W_k + (size_t)i * DM * DM, W_v + (size_t)i * DM * DM,
            b_q + i * DM, b_k + i * DM, b_v + i * DM, qb, kb, vb, LT);
        fattn_kernel<<<gattn, 256, 0, stream>>>(qb, kb, vb, attno);
        mgemm_bias<<<g1, 256, 0, stream>>>(attno, W_o + (size_t)i * DM * DM,
                                           b_o + i * DM, proj, LT);
        gate1add_kernel<<<ew, 256, 0, stream>>>(xn, proj, attno, P);  // attno := y2
        lnmod_kernel<<<LT, 256, 0, stream>>>(attno, xn, P, 1024);
        mgemm_geglu<<<gglu, 256, 0, stream>>>(xn, W_geglu + (size_t)i * DM * 4096,
                                              b_geglu + i * 4096, hbuf, LT);
        mgemm_ffout<<<g1, 256, 0, stream>>>(hbuf, W_ffout + (size_t)i * HIDDEN * DM,
                                            b_ffout + i * DM, proj, LT);
        gate2_kernel<<<ew, 256, 0, stream>>>(proj, state, P);
    }
    unpatch_kernel<<<(DURZ * 3 * 32 * 32 + 255) / 256, 256, 0, stream>>>(
        state, W_unpatch, b_unpatch, (float*)d_out);
}

// Round 2
// 2172.830 us; speedup vs baseline: 1.4992x; 1.2046x over previous
//
#include <hip/hip_runtime.h>
#include <hip/hip_bf16.h>
#include <math.h>

// ---- problem constants ----
#define DURZ 6
#define DURX 5
#define SEQ 257
#define LZ 1542   // 6*257 zr tokens
#define LX 1285   // 5*257 xa tokens
#define LT 2827   // LZ+LX
#define DM 512
#define NHEADS 8
#define DH 64
#define HIDDEN 2048

typedef __bf16 bf16x8 __attribute__((ext_vector_type(8)));
typedef __bf16 bf16x4 __attribute__((ext_vector_type(4)));
typedef float f32x4 __attribute__((ext_vector_type(4)));

// ---------------- sentinel fill (diagnostic readout channel) ----------------
__global__ void fill_kernel(float* __restrict__ out, int n, float v) {
    int i = blockIdx.x * blockDim.x + threadIdx.x;
    if (i < n) out[i] = v;
}

// ---------------- embed ----------------
__global__ void embed_kernel(const float* __restrict__ z,
                             const float* __restrict__ frames,
                             const int* __restrict__ actions,
                             const float* __restrict__ W_patch,
                             const float* __restrict__ b_patch,
                             const float* __restrict__ registers,
                             const float* __restrict__ pe,
                             const float* __restrict__ action_emb,
                             float* __restrict__ state) {
    int T = blockIdx.x;
    int tid = threadIdx.x;
    bool is_z = T < LZ;
    int T2 = is_z ? T : T - LZ;
    int f = T2 / SEQ, t = T2 % SEQ;
    if (t < 256) {
        const float* src = is_z ? z : frames;
        int hp = t >> 4, wp = t & 15;
        float pv[12];
#pragma unroll
        for (int c = 0; c < 3; c++)
#pragma unroll
            for (int ph = 0; ph < 2; ph++)
#pragma unroll
                for (int pw = 0; pw < 2; pw++)
                    pv[c * 4 + ph * 2 + pw] =
                        src[((f * 3 + c) * 32 + (hp * 2 + ph)) * 32 + (wp * 2 + pw)];
        for (int d = tid; d < DM; d += 256) {
            float acc = b_patch[d];
#pragma unroll
            for (int j = 0; j < 12; j++) acc += pv[j] * W_patch[j * DM + d];
            acc += pe[t * DM + d];
            state[T * DM + d] = acc;
        }
    } else if (is_z) {
        for (int d = tid; d < DM; d += 256) state[T * DM + d] = registers[d];
    } else {
        int a = actions[f];
        for (int d = tid; d < DM; d += 256) state[T * DM + d] = action_emb[a * DM + d];
    }
}

// ---------------- cond vectors ----------------
__global__ void cond_kernel(const int* __restrict__ ts,
                            const float* __restrict__ time_emb,
                            float* __restrict__ condraw,
                            float* __restrict__ condsilu) {
    int idx = blockIdx.x * blockDim.x + threadIdx.x;
    if (idx >= 7 * 512) return;
    int r = idx >> 9;
    int j = idx & 511;
    int tsr = (r < 6) ? ts[r] : 0;
    float x = time_emb[tsr * 512 + j];
    condraw[idx] = x;
    condsilu[idx] = x / (1.0f + expf(-x));
}

// ---------------- params[i][r][c] ----------------
__global__ void params_kernel(const float* __restrict__ condraw,
                              const float* __restrict__ condsilu,
                              const float* __restrict__ W_mod1,
                              const float* __restrict__ b_mod1,
                              const float* __restrict__ W_mod2,
                              const float* __restrict__ b_mod2,
                              const float* __restrict__ W_g1,
                              const float* __restrict__ b_g1,
                              const float* __restrict__ W_g2,
                              const float* __restrict__ b_g2,
                              float* __restrict__ params) {
    int idx = blockIdx.x * blockDim.x + threadIdx.x;
    if (idx >= 6 * 7 * 3072) return;
    int i = idx / 21504;
    int rem = idx % 21504;
    int r = rem / 3072;
    int c = rem % 3072;
    const float* cv;
    const float* W;
    float bias;
    int ldw;
    if (c < 1024) {
        cv = condsilu + r * 512;
        W = W_mod1 + (size_t)i * 512 * 1024 + c; ldw = 1024;
        bias = b_mod1[i * 1024 + c];
    } else if (c < 2048) {
        int cc = c - 1024;
        cv = condsilu + r * 512;
        W = W_mod2 + (size_t)i * 512 * 1024 + cc; ldw = 1024;
        bias = b_mod2[i * 1024 + cc];
    } else if (c < 2560) {
        int cc = c - 2048;
        cv = condraw + r * 512;
        W = W_g1 + (size_t)i * 512 * 512 + cc; ldw = 512;
        bias = b_g1[i * 512 + cc];
    } else {
        int cc = c - 2560;
        cv = condraw + r * 512;
        W = W_g2 + (size_t)i * 512 * 512 + cc; ldw = 512;
        bias = b_g2[i * 512 + cc];
    }
    float acc = bias;
    for (int j = 0; j < 512; j++) acc += cv[j] * W[(size_t)j * ldw];
    params[idx] = acc;
}

// ---------------- LN + AdaLN modulate ------------
__global__ __launch_bounds__(256) void lnmod_kernel(const float* __restrict__ x,
                                                    float* __restrict__ y,
                                                    const float* __restrict__ params,
                                                    int mod_off) {
    int T = blockIdx.x;
    int tid = threadIdx.x;
    int r = (T < LZ) ? (T / SEQ) : 6;
    const float* prow = params + r * 3072 + mod_off;
    const float* xr = x + (size_t)T * DM;
    float v0 = xr[tid], v1 = xr[tid + 256];
    float s_ = v0 + v1, q_ = v0 * v0 + v1 * v1;
#pragma unroll
    for (int off = 32; off; off >>= 1) {
        s_ += __shfl_down(s_, off);
        q_ += __shfl_down(q_, off);
    }
    __shared__ float sh[8];
    int wave = tid >> 6, lane = tid & 63;
    if (lane == 0) { sh[wave] = s_; sh[4 + wave] = q_; }
    __syncthreads();
    float sum = sh[0] + sh[1] + sh[2] + sh[3];
    float sq = sh[4] + sh[5] + sh[6] + sh[7];
    float mu = sum * (1.0f / 512.0f);
    float var = sq * (1.0f / 512.0f) - mu * mu;
    float rstd = rsqrtf(var + 1e-5f);
    int d0 = tid, d1 = tid + 256;
    y[(size_t)T * DM + d0] = (v0 - mu) * rstd * (1.0f + prow[d0]) + prow[512 + d0];
    y[(size_t)T * DM + d1] = (v1 - mu) * rstd * (1.0f + prow[d1]) + prow[512 + d1];
}

// ================= split-precision bf16 MFMA GEMM family =====================
// f32 operands split hi/lo: x = hi + lo, hi=(bf16)x, lo=(bf16)(x-hi).
// A@W ~= Ah@Wh + Ah@Wl + Al@Wh  (3 MFMAs, error ~2^-17 relative).
// Weights are pre-split per layer by wprep_kernel into padded tiles:
//   tile-pair = hi[128][40] then lo[128][40] bf16 (20480 B), tile order
//   [nb][kt] with nb = n/128, kt = k/32. row = n-local, col = k-local.
//   80 B rows -> 2-way-max bank aliasing on b128 frag reads (free, m136).
// B is staged LDS-direct via global_load_lds width=16 (no VGPR round-trip,
// no per-block split VALU). A stays f32->split in-register (changes per op).

#define MFMA3(accv, ah, al, bh, bl)                                            \
    accv = __builtin_amdgcn_mfma_f32_16x16x32_bf16(al, bh, accv, 0, 0, 0);     \
    accv = __builtin_amdgcn_mfma_f32_16x16x32_bf16(ah, bl, accv, 0, 0, 0);     \
    accv = __builtin_amdgcn_mfma_f32_16x16x32_bf16(ah, bh, accv, 0, 0, 0);

__device__ __forceinline__ void split8(const float* v, bf16x8& h, bf16x8& l) {
#pragma unroll
    for (int j = 0; j < 8; ++j) {
        __bf16 hh = (__bf16)v[j];
        h[j] = hh;
        l[j] = (__bf16)(v[j] - (float)hh);
    }
}

// stage nch KB-chunks global->LDS, chunk c handled by wave c%4 (uniform base).
__device__ __forceinline__ void stage_chunks(const char* g, char* l, int nch,
                                             int w, int lane) {
    for (int c = w; c < nch; c += 4)
        __builtin_amdgcn_global_load_lds(
            (const unsigned int*)(g + (c << 10) + (lane << 4)),
            (unsigned int*)(l + (c << 10)), 16, 0, 0);
}

// ---- per-layer weight pre-split/transpose/tile -----------------------------
// Wp float-offset regions: q 0 | k 327680 | v 655360 | o 983040 |
//                          glu 1310720 | ff 3932160 | end 5242880 (21 MB)
__global__ __launch_bounds__(256) void wprep_kernel(const float* __restrict__ Wq,
                                                    const float* __restrict__ Wk,
                                                    const float* __restrict__ Wv,
                                                    const float* __restrict__ Wo,
                                                    const float* __restrict__ Wglu,
                                                    const float* __restrict__ Wff,
                                                    float* __restrict__ Wp) {
    __shared__ __align__(16) __bf16 T[2][128][40];
    int id = blockIdx.x, t = threadIdx.x;
    const float* src;
    int N, nb, kt;
    size_t dstf;
    if (id < 256) {
        int mat = id >> 6, rem = id & 63;
        nb = rem >> 4; kt = rem & 15; N = 512;
        src = mat == 0 ? Wq : mat == 1 ? Wk : mat == 2 ? Wv : Wo;
        dstf = (size_t)mat * 327680 + (size_t)(nb * 16 + kt) * 5120;
    } else if (id < 768) {
        int rem = id - 256;
        nb = rem >> 4; kt = rem & 15; N = 4096; src = Wglu;
        dstf = 1310720 + (size_t)(nb * 16 + kt) * 5120;
    } else {
        int rem = id - 768;
        nb = rem >> 6; kt = rem & 63; N = 512; src = Wff;
        dstf = 3932160 + (size_t)(nb * 64 + kt) * 5120;
    }
    int r = t & 127, ch = t >> 7;
#pragma unroll
    for (int s = 0; s < 16; ++s) {
        int c = s * 2 + ch;
        float x = src[(size_t)(kt * 32 + c) * N + nb * 128 + r];
        __bf16 h = (__bf16)x;
        T[0][r][c] = h;
        T[1][r][c] = (__bf16)(x - (float)h);
    }
    __syncthreads();
    float4* d = (float4*)(Wp + dstf);
    const float4* s4 = (const float4*)(&T[0][0][0]);
    for (int i = t; i < 1280; i += 256) d[i] = s4[i];
}

// ---- fused q/k/v projection, BM=64 x BN=128 --------------------------------
__global__ __launch_bounds__(256) void mgemm_qkv(const float* __restrict__ A,
                                                 const float* __restrict__ Wp,
                                                 const float* __restrict__ bq,
                                                 const float* __restrict__ bk,
                                                 const float* __restrict__ bv,
                                                 float* __restrict__ Cq,
                                                 float* __restrict__ Ck,
                                                 float* __restrict__ Cv, int M) {
    __shared__ __align__(16) __bf16 Ah[64][40], Al[64][40];
    __shared__ __align__(16) __bf16 B2[2][128][40];
    const int K = 512, N = 512;
    int tid = threadIdx.x;
    int sel = blockIdx.x >> 2;
    int nb = blockIdx.x & 3;
    int n0 = nb * 128;
    int m0 = blockIdx.y * 64;
    const float* bias = sel == 0 ? bq : (sel == 1 ? bk : bv);
    float* C = sel == 0 ? Cq : (sel == 1 ? Ck : Cv);
    const char* breg = (const char*)Wp + (size_t)sel * 1310720 + (size_t)nb * 16 * 20480;
    int w = tid >> 6, lane = tid & 63;
    int wm = (w >> 1) * 32, wn = (w & 1) * 64;
    int q = lane >> 4, lr = lane & 15;
    int row = tid >> 2, kc = (tid & 3) * 8;
    bool mval = (m0 + row) < M;
    f32x4 acc[2][4];
#pragma unroll
    for (int i = 0; i < 2; ++i)
#pragma unroll
        for (int j = 0; j < 4; ++j)
#pragma unroll
            for (int r = 0; r < 4; ++r) acc[i][j][r] = 0.0f;
    for (int kt = 0; kt < 16; ++kt) {
        float av[8];
        const float* ap = A + (size_t)(m0 + row) * K + kt * 32 + kc;
        float4 t0 = mval ? *(const float4*)(ap) : make_float4(0, 0, 0, 0);
        float4 t1 = mval ? *(const float4*)(ap + 4) : make_float4(0, 0, 0, 0);
        av[0] = t0.x; av[1] = t0.y; av[2] = t0.z; av[3] = t0.w;
        av[4] = t1.x; av[5] = t1.y; av[6] = t1.z; av[7] = t1.w;
        __syncthreads();
        stage_chunks(breg + (size_t)kt * 20480, (char*)(&B2[0][0][0]), 20, w, lane);
        bf16x8 h8, l8;
        split8(av, h8, l8);
        *(bf16x8*)&Ah[row][kc] = h8;
        *(bf16x8*)&Al[row][kc] = l8;
        __syncthreads();
        bf16x8 afh[2], afl[2], bfh[4], bfl[4];
#pragma unroll
        for (int i = 0; i < 2; ++i) {
            afh[i] = *(const bf16x8*)(&Ah[wm + i * 16 + lr][q * 8]);
            afl[i] = *(const bf16x8*)(&Al[wm + i * 16 + lr][q * 8]);
        }
#pragma unroll
        for (int j = 0; j < 4; ++j) {
            bfh[j] = *(const bf16x8*)(&B2[0][wn + j * 16 + lr][q * 8]);
            bfl[j] = *(const bf16x8*)(&B2[1][wn + j * 16 + lr][q * 8]);
        }
#pragma unroll
        for (int i = 0; i < 2; ++i)
#pragma unroll
            for (int j = 0; j < 4; ++j) {
                MFMA3(acc[i][j], afh[i], afl[i], bfh[j], bfl[j]);
            }
    }
#pragma unroll
    for (int i = 0; i < 2; ++i)
#pragma unroll
        for (int r = 0; r < 4; ++r) {
            int m = m0 + wm + i * 16 + q * 4 + r;
            if (m < M) {
#pragma unroll
                for (int j = 0; j < 4; ++j) {
                    int n = n0 + wn + j * 16 + lr;
                    C[(size_t)m * N + n] = acc[i][j][r] + bias[n];
                }
            }
        }
}

// ---- generic BM=64 x BN=128 projection (o-proj, ffout) ---------------------
__global__ __launch_bounds__(256) void mgemm64(const float* __restrict__ A,
                                               const float* __restrict__ Wpreg,
                                               int KT, int K,
                                               const float* __restrict__ bias,
                                               float* __restrict__ C, int M) {
    __shared__ __align__(16) __bf16 Ah[64][40], Al[64][40];
    __shared__ __align__(16) __bf16 B2[2][128][40];
    const int N = 512;
    int tid = threadIdx.x;
    int nb = blockIdx.x;
    int n0 = nb * 128;
    int m0 = blockIdx.y * 64;
    const char* breg = (const char*)Wpreg + (size_t)nb * KT * 20480;
    int w = tid >> 6, lane = tid & 63;
    int wm = (w >> 1) * 32, wn = (w & 1) * 64;
    int q = lane >> 4, lr = lane & 15;
    int row = tid >> 2, kc = (tid & 3) * 8;
    bool mval = (m0 + row) < M;
    f32x4 acc[2][4];
#pragma unroll
    for (int i = 0; i < 2; ++i)
#pragma unroll
        for (int j = 0; j < 4; ++j)
#pragma unroll
            for (int r = 0; r < 4; ++r) acc[i][j][r] = 0.0f;
    for (int kt = 0; kt < KT; ++kt) {
        float av[8];
        const float* ap = A + (size_t)(m0 + row) * K + kt * 32 + kc;
        float4 t0 = mval ? *(const float4*)(ap) : make_float4(0, 0, 0, 0);
        float4 t1 = mval ? *(const float4*)(ap + 4) : make_float4(0, 0, 0, 0);
        av[0] = t0.x; av[1] = t0.y; av[2] = t0.z; av[3] = t0.w;
        av[4] = t1.x; av[5] = t1.y; av[6] = t1.z; av[7] = t1.w;
        __syncthreads();
        stage_chunks(breg + (size_t)kt * 20480, (char*)(&B2[0][0][0]), 20, w, lane);
        bf16x8 h8, l8;
        split8(av, h8, l8);
        *(bf16x8*)&Ah[row][kc] = h8;
        *(bf16x8*)&Al[row][kc] = l8;
        __syncthreads();
        bf16x8 afh[2], afl[2], bfh[4], bfl[4];
#pragma unroll
        for (int i = 0; i < 2; ++i) {
            afh[i] = *(const bf16x8*)(&Ah[wm + i * 16 + lr][q * 8]);
            afl[i] = *(const bf16x8*)(&Al[wm + i * 16 + lr][q * 8]);
        }
#pragma unroll
        for (int j = 0; j < 4; ++j) {
            bfh[j] = *(const bf16x8*)(&B2[0][wn + j * 16 + lr][q * 8]);
            bfl[j] = *(const bf16x8*)(&B2[1][wn + j * 16 + lr][q * 8]);
        }
#pragma unroll
        for (int i = 0; i < 2; ++i)
#pragma unroll
            for (int j = 0; j < 4; ++j) {
                MFMA3(acc[i][j], afh[i], afl[i], bfh[j], bfl[j]);
            }
    }
#pragma unroll
    for (int i = 0; i < 2; ++i)
#pragma unroll
        for (int r = 0; r < 4; ++r) {
            int m = m0 + wm + i * 16 + q * 4 + r;
            if (m < M) {
#pragma unroll
                for (int j = 0; j < 4; ++j) {
                    int n = n0 + wn + j * 16 + lr;
                    C[(size_t)m * N + n] = acc[i][j][r] + bias[n];
                }
            }
        }
}

// ---- GEGLU: h[m][n] = (A@Wa+ba)*gelu(A@Wg+bg), BM=128, paired n/n+2048 -----
__global__ __launch_bounds__(256) void mgemm_geglu(const float* __restrict__ A,
                                                   const float* __restrict__ Wpglu,
                                                   const float* __restrict__ bias,
                                                   float* __restrict__ H, int M) {
    __shared__ __align__(16) __bf16 Ah[128][40], Al[128][40];
    __shared__ __align__(16) __bf16 BA[2][128][40];
    __shared__ __align__(16) __bf16 BG[2][128][40];
    const int K = 512;
    int tid = threadIdx.x;
    int nb = blockIdx.x;
    int n0 = nb * 128;
    int m0 = blockIdx.y * 128;
    const char* brega = (const char*)Wpglu + (size_t)nb * 16 * 20480;
    const char* bregg = (const char*)Wpglu + (size_t)(nb + 16) * 16 * 20480;
    int w = tid >> 6, lane = tid & 63;
    int wm = (w >> 1) * 64, wn = (w & 1) * 64;
    int q = lane >> 4, lr = lane & 15;
    int sm = tid & 127, kh = (tid >> 7) * 16;
    bool mval = (m0 + sm) < M;
    f32x4 acca[4][4], accg[4][4];
#pragma unroll
    for (int i = 0; i < 4; ++i)
#pragma unroll
        for (int j = 0; j < 4; ++j)
#pragma unroll
            for (int r = 0; r < 4; ++r) { acca[i][j][r] = 0.0f; accg[i][j][r] = 0.0f; }
    for (int kt = 0; kt < 16; ++kt) {
        float av[16];
        const float* ap = A + (size_t)(m0 + sm) * K + kt * 32 + kh;
#pragma unroll
        for (int c = 0; c < 4; ++c) {
            float4 t = mval ? *(const float4*)(ap + c * 4) : make_float4(0, 0, 0, 0);
            av[c * 4 + 0] = t.x; av[c * 4 + 1] = t.y;
            av[c * 4 + 2] = t.z; av[c * 4 + 3] = t.w;
        }
        __syncthreads();
        stage_chunks(brega + (size_t)kt * 20480, (char*)(&BA[0][0][0]), 20, w, lane);
        stage_chunks(bregg + (size_t)kt * 20480, (char*)(&BG[0][0][0]), 20, w, lane);
        bf16x8 h0, l0, h1, l1;
        split8(av, h0, l0);
        split8(av + 8, h1, l1);
        *(bf16x8*)&Ah[sm][kh] = h0;
        *(bf16x8*)&Ah[sm][kh + 8] = h1;
        *(bf16x8*)&Al[sm][kh] = l0;
        *(bf16x8*)&Al[sm][kh + 8] = l1;
        __syncthreads();
        bf16x8 afh[4], afl[4];
#pragma unroll
        for (int i = 0; i < 4; ++i) {
            afh[i] = *(const bf16x8*)(&Ah[wm + i * 16 + lr][q * 8]);
            afl[i] = *(const bf16x8*)(&Al[wm + i * 16 + lr][q * 8]);
        }
#pragma unroll
        for (int j = 0; j < 4; ++j) {
            bf16x8 bah = *(const bf16x8*)(&BA[0][wn + j * 16 + lr][q * 8]);
            bf16x8 bal = *(const bf16x8*)(&BA[1][wn + j * 16 + lr][q * 8]);
            bf16x8 bgh = *(const bf16x8*)(&BG[0][wn + j * 16 + lr][q * 8]);
            bf16x8 bgl = *(const bf16x8*)(&BG[1][wn + j * 16 + lr][q * 8]);
#pragma unroll
            for (int i = 0; i < 4; ++i) {
                MFMA3(acca[i][j], afh[i], afl[i], bah, bal);
                MFMA3(accg[i][j], afh[i], afl[i], bgh, bgl);
            }
        }
    }
#pragma unroll
    for (int i = 0; i < 4; ++i)
#pragma unroll
        for (int r = 0; r < 4; ++r) {
            int m = m0 + wm + i * 16 + q * 4 + r;
            if (m < M) {
#pragma unroll
                for (int j = 0; j < 4; ++j) {
                    int n = n0 + wn + j * 16 + lr;
                    float a = acca[i][j][r] + bias[n];
                    float g = accg[i][j][r] + bias[2048 + n];
                    float gel = 0.5f * g * (1.0f + erff(g * 0.70710678118654752f));
                    H[(size_t)m * HIDDEN + n] = a * gel;
                }
            }
        }
}

// ---- flash attention: split-precision bf16 MFMA ----------------------------
__global__ __launch_bounds__(256) void fattn_kernel(const float* __restrict__ Q,
                                                    const float* __restrict__ K,
                                                    const float* __restrict__ V,
                                                    float* __restrict__ O) {
    __shared__ __align__(16) __bf16 Kh[64][72], Kl[64][72];
    __shared__ __align__(16) __bf16 Vth[64][72], Vtl[64][72];
    __shared__ __align__(16) __bf16 Ph[4][16][72], Pl[4][16][72];
    int tid = threadIdx.x;
    int w = tid >> 6, lane = tid & 63;
    int lq = lane & 15, lg = lane >> 4;
    int hoff = blockIdx.z * DH;
    int qbase, base0, len0, base1, len1;
    if (blockIdx.y < 6) {
        int f = blockIdx.y;
        qbase = f * SEQ;
        base0 = f * SEQ; len0 = SEQ;
        int jl = f - 4; if (jl < 0) jl = 0;
        base1 = LZ + jl * SEQ; len1 = (f - jl) * SEQ;
    } else {
        int f = blockIdx.y - 6;
        qbase = LZ + f * SEQ;
        base0 = LZ; len0 = (f + 1) * SEQ;
        base1 = 0; len1 = 0;
    }
    int q0 = blockIdx.x * 64;
    int qvalid = SEQ - q0; if (qvalid > 64) qvalid = 64;

    bf16x8 qh[2], ql[2];
    {
        int qr = w * 16 + lq;
        bool v = qr < qvalid;
        const float* qp = Q + (size_t)(qbase + q0 + qr) * DM + hoff + lg * 8;
#pragma unroll
        for (int s = 0; s < 2; ++s) {
            float4 a = v ? *(const float4*)(qp + s * 32) : make_float4(0, 0, 0, 0);
            float4 b = v ? *(const float4*)(qp + s * 32 + 4) : make_float4(0, 0, 0, 0);
            float fa[8] = {a.x, a.y, a.z, a.w, b.x, b.y, b.z, b.w};
#pragma unroll
            for (int j = 0; j < 8; ++j) {
                __bf16 hh = (__bf16)fa[j];
                qh[s][j] = hh;
                ql[s][j] = (__bf16)(fa[j] - (float)hh);
            }
        }
    }
    f32x4 acc[4];
#pragma unroll
    for (int n = 0; n < 4; ++n)
#pragma unroll
        for (int r = 0; r < 4; ++r) acc[n][r] = 0.0f;
    float m_i = -1e30f, l_i = 0.0f;

    for (int rng = 0; rng < 2; ++rng) {
        int base = rng ? base1 : base0;
        int len = rng ? len1 : len0;
        for (int t0 = 0; t0 < len; t0 += 64) {
            int valid = len - t0; if (valid > 64) valid = 64;
            __syncthreads();
            {
                int kr = tid >> 2, kc = (tid & 3) * 16;
                const float* kp = K + (size_t)(base + t0 + kr) * DM + hoff + kc;
                bool v = kr < valid;
                bf16x8 h0, h1, l0, l1;
#pragma unroll
                for (int c = 0; c < 4; ++c) {
                    float4 t4 = v ? *(const float4*)(kp + c * 4) : make_float4(0, 0, 0, 0);
                    float f4a[4] = {t4.x, t4.y, t4.z, t4.w};
#pragma unroll
                    for (int j = 0; j < 4; ++j) {
                        int idx = c * 4 + j;
                        __bf16 hh = (__bf16)f4a[j];
                        __bf16 ll = (__bf16)(f4a[j] - (float)hh);
                        if (idx < 8) { h0[idx] = hh; l0[idx] = ll; }
                        else { h1[idx - 8] = hh; l1[idx - 8] = ll; }
                    }
                }
                *(bf16x8*)&Kh[kr][kc] = h0;
                *(bf16x8*)&Kh[kr][kc + 8] = h1;
                *(bf16x8*)&Kl[kr][kc] = l0;
                *(bf16x8*)&Kl[kr][kc + 8] = l1;
            }
            {
                int d = tid & 63, kq = (tid >> 6) * 16;
                bf16x8 h0, h1, l0, l1;
#pragma unroll
                for (int j = 0; j < 16; ++j) {
                    float x = (kq + j < valid)
                        ? V[(size_t)(base + t0 + kq + j) * DM + hoff + d] : 0.0f;
                    __bf16 hh = (__bf16)x;
                    __bf16 ll = (__bf16)(x - (float)hh);
                    if (j < 8) { h0[j] = hh; l0[j] = ll; }
                    else { h1[j - 8] = hh; l1[j - 8] = ll; }
                }
                *(bf16x8*)&Vth[d][kq] = h0;
                *(bf16x8*)&Vth[d][kq + 8] = h1;
                *(bf16x8*)&Vtl[d][kq] = l0;
                *(bf16x8*)&Vtl[d][kq + 8] = l1;
            }
            __syncthreads();
            f32x4 st[4];
#pragma unroll
            for (int sub = 0; sub < 4; ++sub)
#pragma unroll
                for (int r = 0; r < 4; ++r) st[sub][r] = 0.0f;
#pragma unroll
            for (int sub = 0; sub < 4; ++sub) {
#pragma unroll
                for (int s = 0; s < 2; ++s) {
                    bf16x8 kfh = *(const bf16x8*)(&Kh[sub * 16 + lq][s * 32 + lg * 8]);
                    bf16x8 kfl = *(const bf16x8*)(&Kl[sub * 16 + lq][s * 32 + lg * 8]);
                    MFMA3(st[sub], kfh, kfl, qh[s], ql[s]);
                }
            }
            float p[16];
            float rmax = -1e30f;
#pragma unroll
            for (int sub = 0; sub < 4; ++sub)
#pragma unroll
                for (int r = 0; r < 4; ++r) {
                    int kk = sub * 16 + lg * 4 + r;
                    float sv = (kk < valid) ? st[sub][r] * 0.125f : -1e30f;
                    p[sub * 4 + r] = sv;
                    rmax = fmaxf(rmax, sv);
                }
            rmax = fmaxf(rmax, __shfl_xor(rmax, 16));
            rmax = fmaxf(rmax, __shfl_xor(rmax, 32));
            float mnew = fmaxf(m_i, rmax);
            float alpha = __expf(m_i - mnew);
            float rsum = 0.0f;
#pragma unroll
            for (int i2 = 0; i2 < 16; ++i2) {
                p[i2] = __expf(p[i2] - mnew);
                rsum += p[i2];
            }
            rsum += __shfl_xor(rsum, 16);
            rsum += __shfl_xor(rsum, 32);
            l_i = l_i * alpha + rsum;
            m_i = mnew;
            float ar[4];
#pragma unroll
            for (int r = 0; r < 4; ++r) ar[r] = __shfl(alpha, lg * 4 + r);
#pragma unroll
            for (int n = 0; n < 4; ++n)
#pragma unroll
                for (int r = 0; r < 4; ++r) acc[n][r] *= ar[r];
#pragma unroll
            for (int sub = 0; sub < 4; ++sub) {
                bf16x4 h4, l4;
#pragma unroll
                for (int r = 0; r < 4; ++r) {
                    float x = p[sub * 4 + r];
                    __bf16 hh = (__bf16)x;
                    h4[r] = hh;
                    l4[r] = (__bf16)(x - (float)hh);
                }
                *(bf16x4*)&Ph[w][lq][sub * 16 + lg * 4] = h4;
                *(bf16x4*)&Pl[w][lq][sub * 16 + lg * 4] = l4;
            }
            bf16x8 pah[2], pal[2];
#pragma unroll
            for (int s = 0; s < 2; ++s) {
                pah[s] = *(const bf16x8*)(&Ph[w][lq][s * 32 + lg * 8]);
                pal[s] = *(const bf16x8*)(&Pl[w][lq][s * 32 + lg * 8]);
            }
#pragma unroll
            for (int n = 0; n < 4; ++n) {
#pragma unroll
                for (int s = 0; s < 2; ++s) {
                    bf16x8 vfh = *(const bf16x8*)(&Vth[n * 16 + lq][s * 32 + lg * 8]);
                    bf16x8 vfl = *(const bf16x8*)(&Vtl[n * 16 + lq][s * 32 + lg * 8]);
                    MFMA3(acc[n], pah[s], pal[s], vfh, vfl);
                }
            }
        }
    }
    float linv[4];
#pragma unroll
    for (int r = 0; r < 4; ++r) linv[r] = 1.0f / __shfl(l_i, lg * 4 + r);
#pragma unroll
    for (int r = 0; r < 4; ++r) {
        int qr = w * 16 + lg * 4 + r;
        if (qr < qvalid) {
            float* op = O + (size_t)(qbase + q0 + qr) * DM + hoff;
#pragma unroll
            for (int n = 0; n < 4; ++n) op[n * 16 + lq] = acc[n][r] * linv[r];
        }
    }
}

// ---------------- gate1 + residual add ----------------
__global__ void gate1add_kernel(const float* __restrict__ xn,
                                const float* __restrict__ proj,
                                float* __restrict__ y2,
                                const float* __restrict__ params) {
    int idx = blockIdx.x * blockDim.x + threadIdx.x;
    if (idx >= LT * DM) return;
    int T = idx >> 9, d = idx & 511;
    int r = (T < LZ) ? (T / SEQ) : 6;
    y2[idx] = xn[idx] * params[r * 3072 + 2048 + d] + proj[idx];
}

// ---------------- gate2 ----------------
__global__ void gate2_kernel(const float* __restrict__ src, float* __restrict__ state,
                             const float* __restrict__ params) {
    int idx = blockIdx.x * blockDim.x + threadIdx.x;
    if (idx >= LT * DM) return;
    int T = idx >> 9, d = idx & 511;
    int r = (T < LZ) ? (T / SEQ) : 6;
    state[idx] = src[idx] * params[r * 3072 + 2560 + d];
}

// ---------------- unpatch to FP32 output ------------------
__global__ void unpatch_kernel(const float* __restrict__ state,
                               const float* __restrict__ Wu,
                               const float* __restrict__ bu,
                               float* __restrict__ out) {
    int idx = blockIdx.x * blockDim.x + threadIdx.x;
    if (idx >= DURZ * 3 * 32 * 32) return;
    int w = idx & 31, hh = (idx >> 5) & 31, c = (idx >> 10) % 3, f = idx / (3 * 1024);
    int t = (hh >> 1) * 16 + (w >> 1);
    int j = c * 4 + (hh & 1) * 2 + (w & 1);
    const float* xr = state + (size_t)(f * SEQ + t) * DM;
    float acc = bu[j];
    for (int k = 0; k < DM; ++k) acc += xr[k] * Wu[k * 12 + j];
    out[idx] = acc;
}

extern "C" void kernel_launch(void* const* d_in, const int* in_sizes, int n_in,
                              void* d_out, int out_size, void* d_ws, size_t ws_size,
                              hipStream_t stream) {
    static const int expected_sizes[32] = {
        18432, 15360, 6, 6,
        6144, 512, 6144, 12,
        512, 131072, 1536, 512000,
        3145728, 6144, 3145728, 6144,
        1572864, 3072, 1572864, 3072,
        1572864, 3072, 1572864, 3072,
        1572864, 3072, 1572864, 3072,
        12582912, 24576, 6291456, 3072
    };
    if (n_in != 32) {
        fill_kernel<<<(18432 + 255) / 256, 256, 0, stream>>>((float*)d_out, 18432, 3.0f);
        return;
    }
    for (int i = 0; i < 32; ++i) {
        if (in_sizes[i] != expected_sizes[i]) {
            fill_kernel<<<(18432 + 255) / 256, 256, 0, stream>>>((float*)d_out, 18432,
                                                                 4.0f + (float)i);
            return;
        }
    }

    const float* z = (const float*)d_in[0];
    const float* frames = (const float*)d_in[1];
    const int* actions = (const int*)d_in[2];
    const int* ts = (const int*)d_in[3];
    const float* W_patch = (const float*)d_in[4];
    const float* b_patch = (const float*)d_in[5];
    const float* W_unpatch = (const float*)d_in[6];
    const float* b_unpatch = (const float*)d_in[7];
    const float* registers = (const float*)d_in[8];
    const float* pe_grid = (const float*)d_in[9];
    const float* action_emb = (const float*)d_in[10];
    const float* time_emb = (const float*)d_in[11];
    const float* W_mod1 = (const float*)d_in[12];
    const float* b_mod1 = (const float*)d_in[13];
    const float* W_mod2 = (const float*)d_in[14];
    const float* b_mod2 = (const float*)d_in[15];
    const float* W_q = (const float*)d_in[16];
    const float* b_q = (const float*)d_in[17];
    const float* W_k = (const float*)d_in[18];
    const float* b_k = (const float*)d_in[19];
    const float* W_v = (const float*)d_in[20];
    const float* b_v = (const float*)d_in[21];
    const float* W_o = (const float*)d_in[22];
    const float* b_o = (const float*)d_in[23];
    const float* W_g1 = (const float*)d_in[24];
    const float* b_g1 = (const float*)d_in[25];
    const float* W_g2 = (const float*)d_in[26];
    const float* b_g2 = (const float*)d_in[27];
    const float* W_geglu = (const float*)d_in[28];
    const float* b_geglu = (const float*)d_in[29];
    const float* W_ffout = (const float*)d_in[30];
    const float* b_ffout = (const float*)d_in[31];

    const size_t S = (size_t)LT * DM;  // 1,447,424
    size_t need = (8 * S + 129024 + 7168 + 5242880) * sizeof(float);
    if (ws_size < need) {
        fill_kernel<<<(18432 + 255) / 256, 256, 0, stream>>>((float*)d_out, 18432, 40.0f);
        return;
    }
    float* ws = (float*)d_ws;
    float* state = ws;
    float* xn = ws + S;
    float* qb = ws + 2 * S;
    float* kb = ws + 3 * S;
    float* vb = ws + 4 * S;
    float* attno = ws + 5 * S;      // reused as y2 after o-proj
    float* proj = ws + 6 * S;
    float* params = ws + 8 * S;
    float* condraw = params + 129024;
    float* condsilu = condraw + 3584;
    float* wp = condsilu + 3584;    // 5,242,880 floats of pre-split weight tiles
    float* hbuf = qb;               // LT x 2048 f32 = 4S region (q/k/v/attno dead)

    embed_kernel<<<LT, 256, 0, stream>>>(z, frames, actions, W_patch, b_patch,
                                         registers, pe_grid, action_emb, state);
    cond_kernel<<<(7 * 512 + 255) / 256, 256, 0, stream>>>(ts, time_emb, condraw, condsilu);
    params_kernel<<<(6 * 7 * 3072 + 255) / 256, 256, 0, stream>>>(
        condraw, condsilu, W_mod1, b_mod1, W_mod2, b_mod2, W_g1, b_g1, W_g2, b_g2, params);

    const int MT64 = (LT + 63) / 64;  // 45
    dim3 gqkv(12, MT64);
    dim3 g64(4, MT64);
    dim3 gglu(16, (LT + 127) / 128);
    dim3 gattn(5, 11, NHEADS);
    int ew = (LT * DM + 255) / 256;
    for (int i = 0; i < 6; ++i) {
        const float* P = params + i * 21504;
        wprep_kernel<<<1024, 256, 0, stream>>>(
            W_q + (size_t)i * DM * DM, W_k + (size_t)i * DM * DM,
            W_v + (size_t)i * DM * DM, W_o + (size_t)i * DM * DM,
            W_geglu + (size_t)i * DM * 4096, W_ffout + (size_t)i * HIDDEN * DM, wp);
        lnmod_kernel<<<LT, 256, 0, stream>>>(state, xn, P, 0);
        mgemm_qkv<<<gqkv, 256, 0, stream>>>(xn, wp, b_q + i * DM, b_k + i * DM,
                                            b_v + i * DM, qb, kb, vb, LT);
        fattn_kernel<<<gattn, 256, 0, stream>>>(qb, kb, vb, attno);
        mgemm64<<<g64, 256, 0, stream>>>(attno, wp + 983040, 16, 512,
                                         b_o + i * DM, proj, LT);
        gate1add_kernel<<<ew, 256, 0, stream>>>(xn, proj, attno, P);  // attno := y2
        lnmod_kernel<<<LT, 256, 0, stream>>>(attno, xn, P, 1024);
        mgemm_geglu<<<gglu, 256, 0, stream>>>(xn, wp + 1310720,
                                              b_geglu + i * 4096, hbuf, LT);
        mgemm64<<<g64, 256, 0, stream>>>(hbuf, wp + 3932160, 64, 2048,
                                         b_ffout + i * DM, proj, LT);
        gate2_kernel<<<ew, 256, 0, stream>>>(proj, state, P);
    }
    unpatch_kernel<<<(DURZ * 3 * 32 * 32 + 255) / 256, 256, 0, stream>>>(
        state, W_unpatch, b_unpatch, (float*)d_out);
}

// Round 3
// 1974.052 us; speedup vs baseline: 1.6502x; 1.1007x over previous
//
#include <hip/hip_runtime.h>
#include <hip/hip_bf16.h>
#include <math.h>

// ---- problem constants ----
#define DURZ 6
#define DURX 5
#define SEQ 257
#define LZ 1542   // 6*257 zr tokens
#define LX 1285   // 5*257 xa tokens
#define LT 2827   // LZ+LX
#define DM 512
#define NHEADS 8
#define DH 64
#define HIDDEN 2048

typedef __bf16 bf16x8 __attribute__((ext_vector_type(8)));
typedef __bf16 bf16x4 __attribute__((ext_vector_type(4)));
typedef float f32x4 __attribute__((ext_vector_type(4)));

// ---------------- sentinel fill (diagnostic readout channel) ----------------
__global__ void fill_kernel(float* __restrict__ out, int n, float v) {
    int i = blockIdx.x * blockDim.x + threadIdx.x;
    if (i < n) out[i] = v;
}

// ---------------- embed ----------------
__global__ void embed_kernel(const float* __restrict__ z,
                             const float* __restrict__ frames,
                             const int* __restrict__ actions,
                             const float* __restrict__ W_patch,
                             const float* __restrict__ b_patch,
                             const float* __restrict__ registers,
                             const float* __restrict__ pe,
                             const float* __restrict__ action_emb,
                             float* __restrict__ state) {
    int T = blockIdx.x;
    int tid = threadIdx.x;
    bool is_z = T < LZ;
    int T2 = is_z ? T : T - LZ;
    int f = T2 / SEQ, t = T2 % SEQ;
    if (t < 256) {
        const float* src = is_z ? z : frames;
        int hp = t >> 4, wp = t & 15;
        float pv[12];
#pragma unroll
        for (int c = 0; c < 3; c++)
#pragma unroll
            for (int ph = 0; ph < 2; ph++)
#pragma unroll
                for (int pw = 0; pw < 2; pw++)
                    pv[c * 4 + ph * 2 + pw] =
                        src[((f * 3 + c) * 32 + (hp * 2 + ph)) * 32 + (wp * 2 + pw)];
        for (int d = tid; d < DM; d += 256) {
            float acc = b_patch[d];
#pragma unroll
            for (int j = 0; j < 12; j++) acc += pv[j] * W_patch[j * DM + d];
            acc += pe[t * DM + d];
            state[T * DM + d] = acc;
        }
    } else if (is_z) {
        for (int d = tid; d < DM; d += 256) state[T * DM + d] = registers[d];
    } else {
        int a = actions[f];
        for (int d = tid; d < DM; d += 256) state[T * DM + d] = action_emb[a * DM + d];
    }
}

// ---------------- cond vectors ----------------
__global__ void cond_kernel(const int* __restrict__ ts,
                            const float* __restrict__ time_emb,
                            float* __restrict__ condraw,
                            float* __restrict__ condsilu) {
    int idx = blockIdx.x * blockDim.x + threadIdx.x;
    if (idx >= 7 * 512) return;
    int r = idx >> 9;
    int j = idx & 511;
    int tsr = (r < 6) ? ts[r] : 0;
    float x = time_emb[tsr * 512 + j];
    condraw[idx] = x;
    condsilu[idx] = x / (1.0f + expf(-x));
}

// ---------------- params[i][r][c] ----------------
__global__ void params_kernel(const float* __restrict__ condraw,
                              const float* __restrict__ condsilu,
                              const float* __restrict__ W_mod1,
                              const float* __restrict__ b_mod1,
                              const float* __restrict__ W_mod2,
                              const float* __restrict__ b_mod2,
                              const float* __restrict__ W_g1,
                              const float* __restrict__ b_g1,
                              const float* __restrict__ W_g2,
                              const float* __restrict__ b_g2,
                              float* __restrict__ params) {
    int idx = blockIdx.x * blockDim.x + threadIdx.x;
    if (idx >= 6 * 7 * 3072) return;
    int i = idx / 21504;
    int rem = idx % 21504;
    int r = rem / 3072;
    int c = rem % 3072;
    const float* cv;
    const float* W;
    float bias;
    int ldw;
    if (c < 1024) {
        cv = condsilu + r * 512;
        W = W_mod1 + (size_t)i * 512 * 1024 + c; ldw = 1024;
        bias = b_mod1[i * 1024 + c];
    } else if (c < 2048) {
        int cc = c - 1024;
        cv = condsilu + r * 512;
        W = W_mod2 + (size_t)i * 512 * 1024 + cc; ldw = 1024;
        bias = b_mod2[i * 1024 + cc];
    } else if (c < 2560) {
        int cc = c - 2048;
        cv = condraw + r * 512;
        W = W_g1 + (size_t)i * 512 * 512 + cc; ldw = 512;
        bias = b_g1[i * 512 + cc];
    } else {
        int cc = c - 2560;
        cv = condraw + r * 512;
        W = W_g2 + (size_t)i * 512 * 512 + cc; ldw = 512;
        bias = b_g2[i * 512 + cc];
    }
    float acc = bias;
    for (int j = 0; j < 512; j++) acc += cv[j] * W[(size_t)j * ldw];
    params[idx] = acc;
}

// ---------------- LN + AdaLN modulate -> pre-split bf16 hi/lo planes --------
template<bool PL>
__global__ __launch_bounds__(256) void lnmod_kernel(const float* __restrict__ xf,
                                                    const __bf16* __restrict__ xh,
                                                    const __bf16* __restrict__ xl,
                                                    __bf16* __restrict__ yh,
                                                    __bf16* __restrict__ yl,
                                                    const float* __restrict__ params,
                                                    int mod_off) {
    int T = blockIdx.x;
    int tid = threadIdx.x;
    int r = (T < LZ) ? (T / SEQ) : 6;
    const float* prow = params + r * 3072 + mod_off;
    size_t base = (size_t)T * DM;
    float v0, v1;
    if constexpr (PL) {
        v0 = (float)xh[base + tid] + (float)xl[base + tid];
        v1 = (float)xh[base + tid + 256] + (float)xl[base + tid + 256];
    } else {
        v0 = xf[base + tid];
        v1 = xf[base + tid + 256];
    }
    float s_ = v0 + v1, q_ = v0 * v0 + v1 * v1;
#pragma unroll
    for (int off = 32; off; off >>= 1) {
        s_ += __shfl_down(s_, off);
        q_ += __shfl_down(q_, off);
    }
    __shared__ float sh[8];
    int wave = tid >> 6, lane = tid & 63;
    if (lane == 0) { sh[wave] = s_; sh[4 + wave] = q_; }
    __syncthreads();
    float sum = sh[0] + sh[1] + sh[2] + sh[3];
    float sq = sh[4] + sh[5] + sh[6] + sh[7];
    float mu = sum * (1.0f / 512.0f);
    float var = sq * (1.0f / 512.0f) - mu * mu;
    float rstd = rsqrtf(var + 1e-5f);
    float y0 = (v0 - mu) * rstd * (1.0f + prow[tid]) + prow[512 + tid];
    float y1 = (v1 - mu) * rstd * (1.0f + prow[tid + 256]) + prow[512 + tid + 256];
    __bf16 h0 = (__bf16)y0, h1 = (__bf16)y1;
    yh[base + tid] = h0;
    yl[base + tid] = (__bf16)(y0 - (float)h0);
    yh[base + tid + 256] = h1;
    yl[base + tid + 256] = (__bf16)(y1 - (float)h1);
}

// ================= split-precision bf16 MFMA GEMM family =====================
// A@W ~= Ah@Wh + Ah@Wl + Al@Wh (3 MFMAs). BOTH operands pre-split bf16 planes:
//   weights by wprep (tiles [2][64][40], 10240 B, order [nsub][kt]);
//   activations by their producer (lnmod / fattn / GLU epilogue), row-major
//   [M][Krow] per plane. A tiles staged LDS-direct via global_load_lds with
//   per-lane-swizzled SOURCE (slot ^= (row>>1)&3) + same-swizzle frag read
//   -> 2-way bank aliasing (free). B rows padded to 40 (80 B) -> 2-way.
// Double-buffered A and B; next tile's global_load_lds issued BEFORE the
// current tile's MFMAs, so __syncthreads' vmcnt(0) drain overlaps compute.

#define MFMA3(accv, ah, al, bh, bl)                                            \
    accv = __builtin_amdgcn_mfma_f32_16x16x32_bf16(al, bh, accv, 0, 0, 0);     \
    accv = __builtin_amdgcn_mfma_f32_16x16x32_bf16(ah, bl, accv, 0, 0, 0);     \
    accv = __builtin_amdgcn_mfma_f32_16x16x32_bf16(ah, bh, accv, 0, 0, 0);

// ---- per-layer weight pre-split/transpose/tile -----------------------------
// Wp float-offset regions: q 0 | k 327680 | v 655360 | o 983040 |
//                          glu 1310720 | ff 3932160 | end 5242880 (21 MB)
__global__ __launch_bounds__(256) void wprep_kernel(const float* __restrict__ Wq,
                                                    const float* __restrict__ Wk,
                                                    const float* __restrict__ Wv,
                                                    const float* __restrict__ Wo,
                                                    const float* __restrict__ Wglu,
                                                    const float* __restrict__ Wff,
                                                    float* __restrict__ Wp) {
    __shared__ __align__(16) __bf16 T[2][64][40];
    int id = blockIdx.x, t = threadIdx.x;
    const float* src;
    int N, nsub, kt;
    size_t dstf;
    if (id < 512) {
        int mat = id >> 7, rem = id & 127;
        nsub = rem >> 4; kt = rem & 15; N = 512;
        src = mat == 0 ? Wq : mat == 1 ? Wk : mat == 2 ? Wv : Wo;
        dstf = (size_t)mat * 327680 + (size_t)(nsub * 16 + kt) * 2560;
    } else if (id < 1536) {
        int rem = id - 512;
        nsub = rem >> 4; kt = rem & 15; N = 4096; src = Wglu;
        dstf = 1310720 + (size_t)(nsub * 16 + kt) * 2560;
    } else {
        int rem = id - 1536;
        nsub = rem >> 6; kt = rem & 63; N = 512; src = Wff;
        dstf = 3932160 + (size_t)(nsub * 64 + kt) * 2560;
    }
    int r = t >> 2;
    int cb = (t & 3) * 8;
#pragma unroll
    for (int j = 0; j < 8; ++j) {
        int c = cb + j;
        float x = src[(size_t)(kt * 32 + c) * N + nsub * 64 + r];
        __bf16 h = (__bf16)x;
        T[0][r][c] = h;
        T[1][r][c] = (__bf16)(x - (float)h);
    }
    __syncthreads();
    float4* d = (float4*)(Wp + dstf);
    const float4* s4 = (const float4*)(&T[0][0][0]);
    for (int i2 = t; i2 < 640; i2 += 256) d[i2] = s4[i2];
}

#define M_QKV 0
#define M_GATE1 1
#define M_GLU 2
#define M_GATE2 3

// one uniform 64x128 GEMM: BM=64, BN=128 (two 64-col subtiles), BK=32,
// 4 waves (2M x 2N). MODE selects B addressing + epilogue fusion.
template<int MODE>
__global__ __launch_bounds__(256) void gemm_kernel(
    const __bf16* __restrict__ Aph, const __bf16* __restrict__ Apl,
    const char* __restrict__ Wbase, int KT, int Krow,
    const float* __restrict__ b0, const float* __restrict__ b1,
    const float* __restrict__ b2,
    float* __restrict__ C0, float* __restrict__ C1, float* __restrict__ C2,
    __bf16* __restrict__ Oh, __bf16* __restrict__ Ol,
    const __bf16* __restrict__ Xh, const __bf16* __restrict__ Xl,
    const float* __restrict__ params, int M) {
    __shared__ __align__(16) __bf16 Alds[2][2][64][32];        // buf, plane
    __shared__ __align__(16) __bf16 Blds[2][2][2][64][40];     // buf, sub, plane
    int tid = threadIdx.x;
    int w = tid >> 6, lane = tid & 63;
    int q = lane >> 4, lr = lane & 15;
    // XCD-chunked bijective swizzle (m-fastest within an XCD -> B L2-local)
    int nwg = gridDim.x * gridDim.y;
    int lin = blockIdx.y * gridDim.x + blockIdx.x;
    int qq = nwg >> 3, rr = nwg & 7;
    int xcd = lin & 7, ix = lin >> 3;
    int wg = (xcd < rr) ? xcd * (qq + 1) + ix : rr * (qq + 1) + (xcd - rr) * qq + ix;
    int mb = wg % gridDim.x;
    int nb = wg / gridDim.x;
    int m0 = mb * 64;
    const char* sb0;
    const char* sb1;
    if constexpr (MODE == M_QKV) {
        int sel = nb >> 2;
        const char* mbp = Wbase + (size_t)sel * 1310720;
        sb0 = mbp + (size_t)(2 * (nb & 3)) * 163840;
        sb1 = mbp + (size_t)(2 * (nb & 3) + 1) * 163840;
    } else if constexpr (MODE == M_GLU) {
        sb0 = Wbase + (size_t)nb * 163840;              // a-cols subtile
        sb1 = Wbase + (size_t)(32 + nb) * 163840;       // g-cols subtile
    } else {
        sb0 = Wbase + (size_t)(2 * nb) * (size_t)KT * 10240;
        sb1 = Wbase + (size_t)(2 * nb + 1) * (size_t)KT * 10240;
    }
    int wm = (w >> 1) * 32;

    auto stage = [&](int sbuf, int kt) {
        const char* k0 = sb0 + (size_t)kt * 10240;
        const char* k1 = sb1 + (size_t)kt * 10240;
        char* bl = (char*)(&Blds[sbuf][0][0][0][0]);
        for (int idx = w; idx < 20; idx += 4) {
            int sub = idx & 1, c = idx >> 1;
            const char* g = (sub ? k1 : k0) + (c << 10) + (lane << 4);
            __builtin_amdgcn_global_load_lds((const unsigned int*)g,
                (unsigned int*)(bl + sub * 10240 + (c << 10)), 16, 0, 0);
        }
        char* al = (char*)(&Alds[sbuf][0][0][0]);
        for (int idx = w; idx < 8; idx += 4) {
            int p = idx & 1, c = idx >> 1;
            int row = c * 16 + (lane >> 2);
            int ss = (lane & 3) ^ ((row >> 1) & 3);
            int mrow = m0 + row;
            if (mrow > M - 1) mrow = M - 1;
            const __bf16* ap = (p ? Apl : Aph) + (size_t)mrow * Krow + kt * 32 + ss * 8;
            __builtin_amdgcn_global_load_lds((const unsigned int*)ap,
                (unsigned int*)(al + p * 4096 + (c << 10)), 16, 0, 0);
        }
    };

    f32x4 acc[2][4];
#pragma unroll
    for (int i = 0; i < 2; ++i)
#pragma unroll
        for (int j = 0; j < 4; ++j)
#pragma unroll
            for (int r = 0; r < 4; ++r) acc[i][j][r] = 0.0f;

    stage(0, 0);
    __syncthreads();
    for (int kt = 0; kt < KT; ++kt) {
        int buf = kt & 1;
        if (kt + 1 < KT) stage(buf ^ 1, kt + 1);   // prefetch: drained by barrier
        bf16x8 afh[2], afl[2], bh[4], bl4[4];
#pragma unroll
        for (int i = 0; i < 2; ++i) {
            int row = wm + i * 16 + lr;
            int off = (q * 16) ^ (((row >> 1) & 3) << 4);
            afh[i] = *(const bf16x8*)((const char*)(&Alds[buf][0][row][0]) + off);
            afl[i] = *(const bf16x8*)((const char*)(&Alds[buf][1][row][0]) + off);
        }
#pragma unroll
        for (int j = 0; j < 4; ++j) {
            int bsub, brow;
            if constexpr (MODE == M_GLU) {
                bsub = j >> 1;
                brow = (w & 1) * 32 + (j & 1) * 16 + lr;
            } else {
                bsub = w & 1;
                brow = j * 16 + lr;
            }
            bh[j] = *(const bf16x8*)(&Blds[buf][bsub][0][brow][q * 8]);
            bl4[j] = *(const bf16x8*)(&Blds[buf][bsub][1][brow][q * 8]);
        }
#pragma unroll
        for (int i = 0; i < 2; ++i)
#pragma unroll
            for (int j = 0; j < 4; ++j) {
                MFMA3(acc[i][j], afh[i], afl[i], bh[j], bl4[j]);
            }
        __syncthreads();
    }

#pragma unroll
    for (int i = 0; i < 2; ++i)
#pragma unroll
        for (int r = 0; r < 4; ++r) {
            int m = m0 + wm + i * 16 + q * 4 + r;
            if (m >= M) continue;
            if constexpr (MODE == M_QKV) {
                int sel = nb >> 2;
                const float* bias = sel == 0 ? b0 : (sel == 1 ? b1 : b2);
                float* C = sel == 0 ? C0 : (sel == 1 ? C1 : C2);
                int c0 = (nb & 3) * 128 + (w & 1) * 64;
#pragma unroll
                for (int j = 0; j < 4; ++j) {
                    int n = c0 + j * 16 + lr;
                    C[(size_t)m * 512 + n] = acc[i][j][r] + bias[n];
                }
            } else if constexpr (MODE == M_GATE1) {
                int r6 = (m < LZ) ? (m / SEQ) : 6;
                const float* g1 = params + r6 * 3072 + 2048;
                int c0 = nb * 128 + (w & 1) * 64;
#pragma unroll
                for (int j = 0; j < 4; ++j) {
                    int n = c0 + j * 16 + lr;
                    size_t o = (size_t)m * 512 + n;
                    float x = (float)Xh[o] + (float)Xl[o];
                    float v = x * g1[n] + acc[i][j][r] + b0[n];
                    __bf16 hh = (__bf16)v;
                    Oh[o] = hh;
                    Ol[o] = (__bf16)(v - (float)hh);
                }
            } else if constexpr (MODE == M_GLU) {
#pragma unroll
                for (int j = 0; j < 2; ++j) {
                    int n = nb * 64 + (w & 1) * 32 + j * 16 + lr;
                    float a = acc[i][j][r] + b0[n];
                    float g = acc[i][j + 2][r] + b0[2048 + n];
                    float gel = 0.5f * g * (1.0f + erff(g * 0.70710678118654752f));
                    float v = a * gel;
                    size_t o = (size_t)m * 2048 + n;
                    __bf16 hh = (__bf16)v;
                    Oh[o] = hh;
                    Ol[o] = (__bf16)(v - (float)hh);
                }
            } else {
                int r6 = (m < LZ) ? (m / SEQ) : 6;
                const float* g2 = params + r6 * 3072 + 2560;
                int c0 = nb * 128 + (w & 1) * 64;
#pragma unroll
                for (int j = 0; j < 4; ++j) {
                    int n = c0 + j * 16 + lr;
                    C0[(size_t)m * 512 + n] = (acc[i][j][r] + b0[n]) * g2[n];
                }
            }
        }
}

// ---- flash attention: split-precision bf16 MFMA; O -> hi/lo planes ---------
__global__ __launch_bounds__(256) void fattn_kernel(const float* __restrict__ Q,
                                                    const float* __restrict__ K,
                                                    const float* __restrict__ V,
                                                    __bf16* __restrict__ Oh,
                                                    __bf16* __restrict__ Ol) {
    __shared__ __align__(16) __bf16 Kh[64][72], Kl[64][72];
    __shared__ __align__(16) __bf16 Vth[64][72], Vtl[64][72];
    __shared__ __align__(16) __bf16 Ph[4][16][72], Pl[4][16][72];
    int tid = threadIdx.x;
    int w = tid >> 6, lane = tid & 63;
    int lq = lane & 15, lg = lane >> 4;
    int hoff = blockIdx.z * DH;
    int qbase, base0, len0, base1, len1;
    if (blockIdx.y < 6) {
        int f = blockIdx.y;
        qbase = f * SEQ;
        base0 = f * SEQ; len0 = SEQ;
        int jl = f - 4; if (jl < 0) jl = 0;
        base1 = LZ + jl * SEQ; len1 = (f - jl) * SEQ;
    } else {
        int f = blockIdx.y - 6;
        qbase = LZ + f * SEQ;
        base0 = LZ; len0 = (f + 1) * SEQ;
        base1 = 0; len1 = 0;
    }
    int q0 = blockIdx.x * 64;
    int qvalid = SEQ - q0; if (qvalid > 64) qvalid = 64;

    bf16x8 qh[2], ql[2];
    {
        int qr = w * 16 + lq;
        bool v = qr < qvalid;
        const float* qp = Q + (size_t)(qbase + q0 + qr) * DM + hoff + lg * 8;
#pragma unroll
        for (int s = 0; s < 2; ++s) {
            float4 a = v ? *(const float4*)(qp + s * 32) : make_float4(0, 0, 0, 0);
            float4 b = v ? *(const float4*)(qp + s * 32 + 4) : make_float4(0, 0, 0, 0);
            float fa[8] = {a.x, a.y, a.z, a.w, b.x, b.y, b.z, b.w};
#pragma unroll
            for (int j = 0; j < 8; ++j) {
                __bf16 hh = (__bf16)fa[j];
                qh[s][j] = hh;
                ql[s][j] = (__bf16)(fa[j] - (float)hh);
            }
        }
    }
    f32x4 acc[4];
#pragma unroll
    for (int n = 0; n < 4; ++n)
#pragma unroll
        for (int r = 0; r < 4; ++r) acc[n][r] = 0.0f;
    float m_i = -1e30f, l_i = 0.0f;

    for (int rng = 0; rng < 2; ++rng) {
        int base = rng ? base1 : base0;
        int len = rng ? len1 : len0;
        for (int t0 = 0; t0 < len; t0 += 64) {
            int valid = len - t0; if (valid > 64) valid = 64;
            __syncthreads();
            {
                int kr = tid >> 2, kc = (tid & 3) * 16;
                const float* kp = K + (size_t)(base + t0 + kr) * DM + hoff + kc;
                bool v = kr < valid;
                bf16x8 h0, h1, l0, l1;
#pragma unroll
                for (int c = 0; c < 4; ++c) {
                    float4 t4 = v ? *(const float4*)(kp + c * 4) : make_float4(0, 0, 0, 0);
                    float f4a[4] = {t4.x, t4.y, t4.z, t4.w};
#pragma unroll
                    for (int j = 0; j < 4; ++j) {
                        int idx = c * 4 + j;
                        __bf16 hh = (__bf16)f4a[j];
                        __bf16 ll = (__bf16)(f4a[j] - (float)hh);
                        if (idx < 8) { h0[idx] = hh; l0[idx] = ll; }
                        else { h1[idx - 8] = hh; l1[idx - 8] = ll; }
                    }
                }
                *(bf16x8*)&Kh[kr][kc] = h0;
                *(bf16x8*)&Kh[kr][kc + 8] = h1;
                *(bf16x8*)&Kl[kr][kc] = l0;
                *(bf16x8*)&Kl[kr][kc + 8] = l1;
            }
            {
                int d = tid & 63, kq = (tid >> 6) * 16;
                bf16x8 h0, h1, l0, l1;
#pragma unroll
                for (int j = 0; j < 16; ++j) {
                    float x = (kq + j < valid)
                        ? V[(size_t)(base + t0 + kq + j) * DM + hoff + d] : 0.0f;
                    __bf16 hh = (__bf16)x;
                    __bf16 ll = (__bf16)(x - (float)hh);
                    if (j < 8) { h0[j] = hh; l0[j] = ll; }
                    else { h1[j - 8] = hh; l1[j - 8] = ll; }
                }
                *(bf16x8*)&Vth[d][kq] = h0;
                *(bf16x8*)&Vth[d][kq + 8] = h1;
                *(bf16x8*)&Vtl[d][kq] = l0;
                *(bf16x8*)&Vtl[d][kq + 8] = l1;
            }
            __syncthreads();
            f32x4 st[4];
#pragma unroll
            for (int sub = 0; sub < 4; ++sub)
#pragma unroll
                for (int r = 0; r < 4; ++r) st[sub][r] = 0.0f;
#pragma unroll
            for (int sub = 0; sub < 4; ++sub) {
#pragma unroll
                for (int s = 0; s < 2; ++s) {
                    bf16x8 kfh = *(const bf16x8*)(&Kh[sub * 16 + lq][s * 32 + lg * 8]);
                    bf16x8 kfl = *(const bf16x8*)(&Kl[sub * 16 + lq][s * 32 + lg * 8]);
                    MFMA3(st[sub], kfh, kfl, qh[s], ql[s]);
                }
            }
            float p[16];
            float rmax = -1e30f;
#pragma unroll
            for (int sub = 0; sub < 4; ++sub)
#pragma unroll
                for (int r = 0; r < 4; ++r) {
                    int kk = sub * 16 + lg * 4 + r;
                    float sv = (kk < valid) ? st[sub][r] * 0.125f : -1e30f;
                    p[sub * 4 + r] = sv;
                    rmax = fmaxf(rmax, sv);
                }
            rmax = fmaxf(rmax, __shfl_xor(rmax, 16));
            rmax = fmaxf(rmax, __shfl_xor(rmax, 32));
            float mnew = fmaxf(m_i, rmax);
            float alpha = __expf(m_i - mnew);
            float rsum = 0.0f;
#pragma unroll
            for (int i2 = 0; i2 < 16; ++i2) {
                p[i2] = __expf(p[i2] - mnew);
                rsum += p[i2];
            }
            rsum += __shfl_xor(rsum, 16);
            rsum += __shfl_xor(rsum, 32);
            l_i = l_i * alpha + rsum;
            m_i = mnew;
            float ar[4];
#pragma unroll
            for (int r = 0; r < 4; ++r) ar[r] = __shfl(alpha, lg * 4 + r);
#pragma unroll
            for (int n = 0; n < 4; ++n)
#pragma unroll
                for (int r = 0; r < 4; ++r) acc[n][r] *= ar[r];
#pragma unroll
            for (int sub = 0; sub < 4; ++sub) {
                bf16x4 h4, l4;
#pragma unroll
                for (int r = 0; r < 4; ++r) {
                    float x = p[sub * 4 + r];
                    __bf16 hh = (__bf16)x;
                    h4[r] = hh;
                    l4[r] = (__bf16)(x - (float)hh);
                }
                *(bf16x4*)&Ph[w][lq][sub * 16 + lg * 4] = h4;
                *(bf16x4*)&Pl[w][lq][sub * 16 + lg * 4] = l4;
            }
            bf16x8 pah[2], pal[2];
#pragma unroll
            for (int s = 0; s < 2; ++s) {
                pah[s] = *(const bf16x8*)(&Ph[w][lq][s * 32 + lg * 8]);
                pal[s] = *(const bf16x8*)(&Pl[w][lq][s * 32 + lg * 8]);
            }
#pragma unroll
            for (int n = 0; n < 4; ++n) {
#pragma unroll
                for (int s = 0; s < 2; ++s) {
                    bf16x8 vfh = *(const bf16x8*)(&Vth[n * 16 + lq][s * 32 + lg * 8]);
                    bf16x8 vfl = *(const bf16x8*)(&Vtl[n * 16 + lq][s * 32 + lg * 8]);
                    MFMA3(acc[n], pah[s], pal[s], vfh, vfl);
                }
            }
        }
    }
    float linv[4];
#pragma unroll
    for (int r = 0; r < 4; ++r) linv[r] = 1.0f / __shfl(l_i, lg * 4 + r);
#pragma unroll
    for (int r = 0; r < 4; ++r) {
        int qr = w * 16 + lg * 4 + r;
        if (qr < qvalid) {
            size_t ob = (size_t)(qbase + q0 + qr) * DM + hoff;
#pragma unroll
            for (int n = 0; n < 4; ++n) {
                float v = acc[n][r] * linv[r];
                __bf16 hh = (__bf16)v;
                Oh[ob + n * 16 + lq] = hh;
                Ol[ob + n * 16 + lq] = (__bf16)(v - (float)hh);
            }
        }
    }
}

// ---------------- unpatch to FP32 output ------------------
__global__ void unpatch_kernel(const float* __restrict__ state,
                               const float* __restrict__ Wu,
                               const float* __restrict__ bu,
                               float* __restrict__ out) {
    int idx = blockIdx.x * blockDim.x + threadIdx.x;
    if (idx >= DURZ * 3 * 32 * 32) return;
    int w = idx & 31, hh = (idx >> 5) & 31, c = (idx >> 10) % 3, f = idx / (3 * 1024);
    int t = (hh >> 1) * 16 + (w >> 1);
    int j = c * 4 + (hh & 1) * 2 + (w & 1);
    const float* xr = state + (size_t)(f * SEQ + t) * DM;
    float acc = bu[j];
    for (int k = 0; k < DM; ++k) acc += xr[k] * Wu[k * 12 + j];
    out[idx] = acc;
}

extern "C" void kernel_launch(void* const* d_in, const int* in_sizes, int n_in,
                              void* d_out, int out_size, void* d_ws, size_t ws_size,
                              hipStream_t stream) {
    static const int expected_sizes[32] = {
        18432, 15360, 6, 6,
        6144, 512, 6144, 12,
        512, 131072, 1536, 512000,
        3145728, 6144, 3145728, 6144,
        1572864, 3072, 1572864, 3072,
        1572864, 3072, 1572864, 3072,
        1572864, 3072, 1572864, 3072,
        12582912, 24576, 6291456, 3072
    };
    if (n_in != 32) {
        fill_kernel<<<(18432 + 255) / 256, 256, 0, stream>>>((float*)d_out, 18432, 3.0f);
        return;
    }
    for (int i = 0; i < 32; ++i) {
        if (in_sizes[i] != expected_sizes[i]) {
            fill_kernel<<<(18432 + 255) / 256, 256, 0, stream>>>((float*)d_out, 18432,
                                                                 4.0f + (float)i);
            return;
        }
    }

    const float* z = (const float*)d_in[0];
    const float* frames = (const float*)d_in[1];
    const int* actions = (const int*)d_in[2];
    const int* ts = (const int*)d_in[3];
    const float* W_patch = (const float*)d_in[4];
    const float* b_patch = (const float*)d_in[5];
    const float* W_unpatch = (const float*)d_in[6];
    const float* b_unpatch = (const float*)d_in[7];
    const float* registers = (const float*)d_in[8];
    const float* pe_grid = (const float*)d_in[9];
    const float* action_emb = (const float*)d_in[10];
    const float* time_emb = (const float*)d_in[11];
    const float* W_mod1 = (const float*)d_in[12];
    const float* b_mod1 = (const float*)d_in[13];
    const float* W_mod2 = (const float*)d_in[14];
    const float* b_mod2 = (const float*)d_in[15];
    const float* W_q = (const float*)d_in[16];
    const float* b_q = (const float*)d_in[17];
    const float* W_k = (const float*)d_in[18];
    const float* b_k = (const float*)d_in[19];
    const float* W_v = (const float*)d_in[20];
    const float* b_v = (const float*)d_in[21];
    const float* W_o = (const float*)d_in[22];
    const float* b_o = (const float*)d_in[23];
    const float* W_g1 = (const float*)d_in[24];
    const float* b_g1 = (const float*)d_in[25];
    const float* W_g2 = (const float*)d_in[26];
    const float* b_g2 = (const float*)d_in[27];
    const float* W_geglu = (const float*)d_in[28];
    const float* b_geglu = (const float*)d_in[29];
    const float* W_ffout = (const float*)d_in[30];
    const float* b_ffout = (const float*)d_in[31];

    const size_t S = (size_t)LT * DM;  // 1,447,424
    size_t need = (7 * S + 129024 + 7168 + 5242880) * sizeof(float);
    if (ws_size < need) {
        fill_kernel<<<(18432 + 255) / 256, 256, 0, stream>>>((float*)d_out, 18432, 40.0f);
        return;
    }
    float* ws = (float*)d_ws;
    float* state = ws;                              // [0, 1S)
    __bf16* xnh = (__bf16*)(ws + S);                // [1S, 1.5S)
    __bf16* xnl = (__bf16*)(ws + S + S / 2);        // [1.5S, 2S)
    float* qb = ws + 2 * S;                         // [2S, 3S)
    float* kb = ws + 3 * S;                         // [3S, 4S)
    float* vb = ws + 4 * S;                         // [4S, 5S)
    __bf16* atth = (__bf16*)(ws + 5 * S);           // [5S, 5.5S)
    __bf16* attl = (__bf16*)(ws + 5 * S + S / 2);   // [5.5S, 6S)
    __bf16* y2h = (__bf16*)(ws + 6 * S);            // [6S, 6.5S)
    __bf16* y2l = (__bf16*)(ws + 6 * S + S / 2);    // [6.5S, 7S)
    __bf16* Hph = (__bf16*)(ws + 2 * S);            // overlay [2S, 4S) (qkv dead)
    __bf16* Hpl = (__bf16*)(ws + 4 * S);            // overlay [4S, 6S) (att dead)
    float* params = ws + 7 * S;
    float* condraw = params + 129024;
    float* condsilu = condraw + 3584;
    float* wp = condsilu + 3584;                    // 5,242,880 floats

    embed_kernel<<<LT, 256, 0, stream>>>(z, frames, actions, W_patch, b_patch,
                                         registers, pe_grid, action_emb, state);
    cond_kernel<<<(7 * 512 + 255) / 256, 256, 0, stream>>>(ts, time_emb, condraw, condsilu);
    params_kernel<<<(6 * 7 * 3072 + 255) / 256, 256, 0, stream>>>(
        condraw, condsilu, W_mod1, b_mod1, W_mod2, b_mod2, W_g1, b_g1, W_g2, b_g2, params);

    dim3 gqkv(45, 12);
    dim3 ggate1(45, 4);
    dim3 gglu(45, 32);
    dim3 ggate2(45, 4);
    dim3 gattn(5, 11, NHEADS);
    for (int i = 0; i < 6; ++i) {
        const float* P = params + i * 21504;
        wprep_kernel<<<2048, 256, 0, stream>>>(
            W_q + (size_t)i * DM * DM, W_k + (size_t)i * DM * DM,
            W_v + (size_t)i * DM * DM, W_o + (size_t)i * DM * DM,
            W_geglu + (size_t)i * DM * 4096, W_ffout + (size_t)i * HIDDEN * DM, wp);
        lnmod_kernel<false><<<LT, 256, 0, stream>>>(state, nullptr, nullptr,
                                                    xnh, xnl, P, 0);
        gemm_kernel<M_QKV><<<gqkv, 256, 0, stream>>>(
            xnh, xnl, (const char*)wp, 16, 512,
            b_q + i * DM, b_k + i * DM, b_v + i * DM, qb, kb, vb,
            nullptr, nullptr, nullptr, nullptr, nullptr, LT);
        fattn_kernel<<<gattn, 256, 0, stream>>>(qb, kb, vb, atth, attl);
        gemm_kernel<M_GATE1><<<ggate1, 256, 0, stream>>>(
            atth, attl, (const char*)(wp + 983040), 16, 512,
            b_o + i * DM, nullptr, nullptr, nullptr, nullptr, nullptr,
            y2h, y2l, xnh, xnl, P, LT);
        lnmod_kernel<true><<<LT, 256, 0, stream>>>(nullptr, y2h, y2l,
                                                   xnh, xnl, P, 1024);
        gemm_kernel<M_GLU><<<gglu, 256, 0, stream>>>(
            xnh, xnl, (const char*)(wp + 1310720), 16, 512,
            b_geglu + (size_t)i * 4096, nullptr, nullptr, nullptr, nullptr, nullptr,
            Hph, Hpl, nullptr, nullptr, nullptr, LT);
        gemm_kernel<M_GATE2><<<ggate2, 256, 0, stream>>>(
            Hph, Hpl, (const char*)(wp + 3932160), 64, 2048,
            b_ffout + i * DM, nullptr, nullptr, state, nullptr, nullptr,
            nullptr, nullptr, nullptr, nullptr, P, LT);
    }
    unpatch_kernel<<<(DURZ * 3 * 32 * 32 + 255) / 256, 256, 0, stream>>>(
        state, W_unpatch, b_unpatch, (float*)d_out);
}

// Round 4
// 1856.212 us; speedup vs baseline: 1.7550x; 1.0635x over previous
//
#include <hip/hip_runtime.h>
#include <hip/hip_bf16.h>
#include <math.h>

// ---- problem constants ----
#define DURZ 6
#define DURX 5
#define SEQ 257
#define LZ 1542   // 6*257 zr tokens
#define LX 1285   // 5*257 xa tokens
#define LT 2827   // LZ+LX
#define LTP 2880  // LT rounded up to 64 (plane row pad for aligned KV tiles)
#define DM 512
#define NHEADS 8
#define DH 64
#define HIDDEN 2048

typedef __bf16 bf16x8 __attribute__((ext_vector_type(8)));
typedef __bf16 bf16x4 __attribute__((ext_vector_type(4)));
typedef float f32x4 __attribute__((ext_vector_type(4)));

// ---------------- sentinel fill (diagnostic readout channel) ----------------
__global__ void fill_kernel(float* __restrict__ out, int n, float v) {
    int i = blockIdx.x * blockDim.x + threadIdx.x;
    if (i < n) out[i] = v;
}

// ---------------- embed ----------------
__global__ void embed_kernel(const float* __restrict__ z,
                             const float* __restrict__ frames,
                             const int* __restrict__ actions,
                             const float* __restrict__ W_patch,
                             const float* __restrict__ b_patch,
                             const float* __restrict__ registers,
                             const float* __restrict__ pe,
                             const float* __restrict__ action_emb,
                             float* __restrict__ state) {
    int T = blockIdx.x;
    int tid = threadIdx.x;
    bool is_z = T < LZ;
    int T2 = is_z ? T : T - LZ;
    int f = T2 / SEQ, t = T2 % SEQ;
    if (t < 256) {
        const float* src = is_z ? z : frames;
        int hp = t >> 4, wp = t & 15;
        float pv[12];
#pragma unroll
        for (int c = 0; c < 3; c++)
#pragma unroll
            for (int ph = 0; ph < 2; ph++)
#pragma unroll
                for (int pw = 0; pw < 2; pw++)
                    pv[c * 4 + ph * 2 + pw] =
                        src[((f * 3 + c) * 32 + (hp * 2 + ph)) * 32 + (wp * 2 + pw)];
        for (int d = tid; d < DM; d += 256) {
            float acc = b_patch[d];
#pragma unroll
            for (int j = 0; j < 12; j++) acc += pv[j] * W_patch[j * DM + d];
            acc += pe[t * DM + d];
            state[T * DM + d] = acc;
        }
    } else if (is_z) {
        for (int d = tid; d < DM; d += 256) state[T * DM + d] = registers[d];
    } else {
        int a = actions[f];
        for (int d = tid; d < DM; d += 256) state[T * DM + d] = action_emb[a * DM + d];
    }
}

// ---------------- cond vectors ----------------
__global__ void cond_kernel(const int* __restrict__ ts,
                            const float* __restrict__ time_emb,
                            float* __restrict__ condraw,
                            float* __restrict__ condsilu) {
    int idx = blockIdx.x * blockDim.x + threadIdx.x;
    if (idx >= 7 * 512) return;
    int r = idx >> 9;
    int j = idx & 511;
    int tsr = (r < 6) ? ts[r] : 0;
    float x = time_emb[tsr * 512 + j];
    condraw[idx] = x;
    condsilu[idx] = x / (1.0f + expf(-x));
}

// ---------------- params[i][r][c] ----------------
__global__ void params_kernel(const float* __restrict__ condraw,
                              const float* __restrict__ condsilu,
                              const float* __restrict__ W_mod1,
                              const float* __restrict__ b_mod1,
                              const float* __restrict__ W_mod2,
                              const float* __restrict__ b_mod2,
                              const float* __restrict__ W_g1,
                              const float* __restrict__ b_g1,
                              const float* __restrict__ W_g2,
                              const float* __restrict__ b_g2,
                              float* __restrict__ params) {
    int idx = blockIdx.x * blockDim.x + threadIdx.x;
    if (idx >= 6 * 7 * 3072) return;
    int i = idx / 21504;
    int rem = idx % 21504;
    int r = rem / 3072;
    int c = rem % 3072;
    const float* cv;
    const float* W;
    float bias;
    int ldw;
    if (c < 1024) {
        cv = condsilu + r * 512;
        W = W_mod1 + (size_t)i * 512 * 1024 + c; ldw = 1024;
        bias = b_mod1[i * 1024 + c];
    } else if (c < 2048) {
        int cc = c - 1024;
        cv = condsilu + r * 512;
        W = W_mod2 + (size_t)i * 512 * 1024 + cc; ldw = 1024;
        bias = b_mod2[i * 1024 + cc];
    } else if (c < 2560) {
        int cc = c - 2048;
        cv = condraw + r * 512;
        W = W_g1 + (size_t)i * 512 * 512 + cc; ldw = 512;
        bias = b_g1[i * 512 + cc];
    } else {
        int cc = c - 2560;
        cv = condraw + r * 512;
        W = W_g2 + (size_t)i * 512 * 512 + cc; ldw = 512;
        bias = b_g2[i * 512 + cc];
    }
    float acc = bias;
    for (int j = 0; j < 512; j++) acc += cv[j] * W[(size_t)j * ldw];
    params[idx] = acc;
}

// ---------------- zero plane tails (once; epilogues never touch rows>=LT) ---
__global__ void ztail_kernel(__bf16* __restrict__ Kh, __bf16* __restrict__ Kl,
                             __bf16* __restrict__ Vth, __bf16* __restrict__ Vtl) {
    int idx = blockIdx.x * blockDim.x + threadIdx.x;
    if (idx >= (LTP - LT) * 512) return;
    int r = idx / 512, c = idx % 512;
    Kh[(size_t)(LT + r) * DM + c] = (__bf16)0.0f;
    Kl[(size_t)(LT + r) * DM + c] = (__bf16)0.0f;
    Vth[(size_t)c * LTP + LT + r] = (__bf16)0.0f;
    Vtl[(size_t)c * LTP + LT + r] = (__bf16)0.0f;
}

// ---------------- LN + AdaLN modulate -> pre-split bf16 hi/lo planes --------
template<bool PL>
__global__ __launch_bounds__(256) void lnmod_kernel(const float* __restrict__ xf,
                                                    const __bf16* __restrict__ xh,
                                                    const __bf16* __restrict__ xl,
                                                    __bf16* __restrict__ yh,
                                                    __bf16* __restrict__ yl,
                                                    const float* __restrict__ params,
                                                    int mod_off) {
    int T = blockIdx.x;
    int tid = threadIdx.x;
    int r = (T < LZ) ? (T / SEQ) : 6;
    const float* prow = params + r * 3072 + mod_off;
    size_t base = (size_t)T * DM;
    float v0, v1;
    if constexpr (PL) {
        v0 = (float)xh[base + tid] + (float)xl[base + tid];
        v1 = (float)xh[base + tid + 256] + (float)xl[base + tid + 256];
    } else {
        v0 = xf[base + tid];
        v1 = xf[base + tid + 256];
    }
    float s_ = v0 + v1, q_ = v0 * v0 + v1 * v1;
#pragma unroll
    for (int off = 32; off; off >>= 1) {
        s_ += __shfl_down(s_, off);
        q_ += __shfl_down(q_, off);
    }
    __shared__ float sh[8];
    int wave = tid >> 6, lane = tid & 63;
    if (lane == 0) { sh[wave] = s_; sh[4 + wave] = q_; }
    __syncthreads();
    float sum = sh[0] + sh[1] + sh[2] + sh[3];
    float sq = sh[4] + sh[5] + sh[6] + sh[7];
    float mu = sum * (1.0f / 512.0f);
    float var = sq * (1.0f / 512.0f) - mu * mu;
    float rstd = rsqrtf(var + 1e-5f);
    float y0 = (v0 - mu) * rstd * (1.0f + prow[tid]) + prow[512 + tid];
    float y1 = (v1 - mu) * rstd * (1.0f + prow[tid + 256]) + prow[512 + tid + 256];
    __bf16 h0 = (__bf16)y0, h1 = (__bf16)y1;
    yh[base + tid] = h0;
    yl[base + tid] = (__bf16)(y0 - (float)h0);
    yh[base + tid + 256] = h1;
    yl[base + tid + 256] = (__bf16)(y1 - (float)h1);
}

// ================= split-precision bf16 MFMA GEMM family =====================
#define MFMA3(accv, ah, al, bh, bl)                                            \
    accv = __builtin_amdgcn_mfma_f32_16x16x32_bf16(al, bh, accv, 0, 0, 0);     \
    accv = __builtin_amdgcn_mfma_f32_16x16x32_bf16(ah, bl, accv, 0, 0, 0);     \
    accv = __builtin_amdgcn_mfma_f32_16x16x32_bf16(ah, bh, accv, 0, 0, 0);

// ---- per-layer weight pre-split/transpose/tile -----------------------------
// Wp float-offset regions: q 0 | k 327680 | v 655360 | o 983040 |
//                          glu 1310720 | ff 3932160 | end 5242880 (21 MB)
__global__ __launch_bounds__(256) void wprep_kernel(const float* __restrict__ Wq,
                                                    const float* __restrict__ Wk,
                                                    const float* __restrict__ Wv,
                                                    const float* __restrict__ Wo,
                                                    const float* __restrict__ Wglu,
                                                    const float* __restrict__ Wff,
                                                    float* __restrict__ Wp) {
    __shared__ __align__(16) __bf16 T[2][64][40];
    int id = blockIdx.x, t = threadIdx.x;
    const float* src;
    int N, nsub, kt;
    size_t dstf;
    if (id < 512) {
        int mat = id >> 7, rem = id & 127;
        nsub = rem >> 4; kt = rem & 15; N = 512;
        src = mat == 0 ? Wq : mat == 1 ? Wk : mat == 2 ? Wv : Wo;
        dstf = (size_t)mat * 327680 + (size_t)(nsub * 16 + kt) * 2560;
    } else if (id < 1536) {
        int rem = id - 512;
        nsub = rem >> 4; kt = rem & 15; N = 4096; src = Wglu;
        dstf = 1310720 + (size_t)(nsub * 16 + kt) * 2560;
    } else {
        int rem = id - 1536;
        nsub = rem >> 6; kt = rem & 63; N = 512; src = Wff;
        dstf = 3932160 + (size_t)(nsub * 64 + kt) * 2560;
    }
    int r = t >> 2;
    int cb = (t & 3) * 8;
#pragma unroll
    for (int j = 0; j < 8; ++j) {
        int c = cb + j;
        float x = src[(size_t)(kt * 32 + c) * N + nsub * 64 + r];
        __bf16 h = (__bf16)x;
        T[0][r][c] = h;
        T[1][r][c] = (__bf16)(x - (float)h);
    }
    __syncthreads();
    float4* d = (float4*)(Wp + dstf);
    const float4* s4 = (const float4*)(&T[0][0][0]);
    for (int i2 = t; i2 < 640; i2 += 256) d[i2] = s4[i2];
}

#define M_QKV 0
#define M_GATE1 1
#define M_GLU 2
#define M_GATE2 3

// one uniform 64x128 GEMM: BM=64, BN=128 (two 64-col subtiles), BK=32,
// 4 waves (2M x 2N). MODE selects B addressing + epilogue fusion.
template<int MODE>
__global__ __launch_bounds__(256) void gemm_kernel(
    const __bf16* __restrict__ Aph, const __bf16* __restrict__ Apl,
    const char* __restrict__ Wbase, int KT, int Krow,
    const float* __restrict__ b0, const float* __restrict__ b1,
    const float* __restrict__ b2,
    float* __restrict__ C0,
    __bf16* __restrict__ Oh, __bf16* __restrict__ Ol,
    __bf16* __restrict__ O2h, __bf16* __restrict__ O2l,
    __bf16* __restrict__ O3h, __bf16* __restrict__ O3l,
    const __bf16* __restrict__ Xh, const __bf16* __restrict__ Xl,
    const float* __restrict__ params, int M) {
    __shared__ __align__(16) __bf16 Alds[2][2][64][32];        // buf, plane
    __shared__ __align__(16) __bf16 Blds[2][2][2][64][40];     // buf, sub, plane
    int tid = threadIdx.x;
    int w = tid >> 6, lane = tid & 63;
    int q = lane >> 4, lr = lane & 15;
    // XCD-chunked bijective swizzle (m-fastest within an XCD -> B L2-local)
    int nwg = gridDim.x * gridDim.y;
    int lin = blockIdx.y * gridDim.x + blockIdx.x;
    int qq = nwg >> 3, rr = nwg & 7;
    int xcd = lin & 7, ix = lin >> 3;
    int wg = (xcd < rr) ? xcd * (qq + 1) + ix : rr * (qq + 1) + (xcd - rr) * qq + ix;
    int mb = wg % gridDim.x;
    int nb = wg / gridDim.x;
    int m0 = mb * 64;
    const char* sb0;
    const char* sb1;
    if constexpr (MODE == M_QKV) {
        int sel = nb >> 2;
        const char* mbp = Wbase + (size_t)sel * 1310720;
        sb0 = mbp + (size_t)(2 * (nb & 3)) * 163840;
        sb1 = mbp + (size_t)(2 * (nb & 3) + 1) * 163840;
    } else if constexpr (MODE == M_GLU) {
        sb0 = Wbase + (size_t)nb * 163840;              // a-cols subtile
        sb1 = Wbase + (size_t)(32 + nb) * 163840;       // g-cols subtile
    } else {
        sb0 = Wbase + (size_t)(2 * nb) * (size_t)KT * 10240;
        sb1 = Wbase + (size_t)(2 * nb + 1) * (size_t)KT * 10240;
    }
    int wm = (w >> 1) * 32;

    auto stage = [&](int sbuf, int kt) {
        const char* k0 = sb0 + (size_t)kt * 10240;
        const char* k1 = sb1 + (size_t)kt * 10240;
        char* bl = (char*)(&Blds[sbuf][0][0][0][0]);
        for (int idx = w; idx < 20; idx += 4) {
            int sub = idx & 1, c = idx >> 1;
            const char* g = (sub ? k1 : k0) + (c << 10) + (lane << 4);
            __builtin_amdgcn_global_load_lds((const unsigned int*)g,
                (unsigned int*)(bl + sub * 10240 + (c << 10)), 16, 0, 0);
        }
        char* al = (char*)(&Alds[sbuf][0][0][0]);
        for (int idx = w; idx < 8; idx += 4) {
            int p = idx & 1, c = idx >> 1;
            int row = c * 16 + (lane >> 2);
            int ss = (lane & 3) ^ ((row >> 1) & 3);
            int mrow = m0 + row;
            if (mrow > M - 1) mrow = M - 1;
            const __bf16* ap = (p ? Apl : Aph) + (size_t)mrow * Krow + kt * 32 + ss * 8;
            __builtin_amdgcn_global_load_lds((const unsigned int*)ap,
                (unsigned int*)(al + p * 4096 + (c << 10)), 16, 0, 0);
        }
    };

    f32x4 acc[2][4];
#pragma unroll
    for (int i = 0; i < 2; ++i)
#pragma unroll
        for (int j = 0; j < 4; ++j)
#pragma unroll
            for (int r = 0; r < 4; ++r) acc[i][j][r] = 0.0f;

    stage(0, 0);
    __syncthreads();
    for (int kt = 0; kt < KT; ++kt) {
        int buf = kt & 1;
        if (kt + 1 < KT) stage(buf ^ 1, kt + 1);   // prefetch: drained by barrier
        bf16x8 afh[2], afl[2], bh[4], bl4[4];
#pragma unroll
        for (int i = 0; i < 2; ++i) {
            int row = wm + i * 16 + lr;
            int off = (q * 16) ^ (((row >> 1) & 3) << 4);
            afh[i] = *(const bf16x8*)((const char*)(&Alds[buf][0][row][0]) + off);
            afl[i] = *(const bf16x8*)((const char*)(&Alds[buf][1][row][0]) + off);
        }
#pragma unroll
        for (int j = 0; j < 4; ++j) {
            int bsub, brow;
            if constexpr (MODE == M_GLU) {
                bsub = j >> 1;
                brow = (w & 1) * 32 + (j & 1) * 16 + lr;
            } else {
                bsub = w & 1;
                brow = j * 16 + lr;
            }
            bh[j] = *(const bf16x8*)(&Blds[buf][bsub][0][brow][q * 8]);
            bl4[j] = *(const bf16x8*)(&Blds[buf][bsub][1][brow][q * 8]);
        }
#pragma unroll
        for (int i = 0; i < 2; ++i)
#pragma unroll
            for (int j = 0; j < 4; ++j) {
                MFMA3(acc[i][j], afh[i], afl[i], bh[j], bl4[j]);
            }
        __syncthreads();
    }

    if constexpr (MODE == M_QKV) {
        int sel = nb >> 2;
        int c0 = (nb & 3) * 128 + (w & 1) * 64;
        if (sel == 2) {
            // V^T hi/lo planes: Vt[(n)][token], 8B vector stores over r
#pragma unroll
            for (int i = 0; i < 2; ++i) {
                int mb2 = m0 + wm + i * 16 + q * 4;
#pragma unroll
                for (int j = 0; j < 4; ++j) {
                    int n = c0 + j * 16 + lr;
                    bf16x4 h4, l4;
#pragma unroll
                    for (int r = 0; r < 4; ++r) {
                        float v = acc[i][j][r] + b2[n];
                        __bf16 hh = (__bf16)v;
                        h4[r] = hh;
                        l4[r] = (__bf16)(v - (float)hh);
                    }
                    if (mb2 + 3 < M) {
                        *(bf16x4*)(O3h + (size_t)n * LTP + mb2) = h4;
                        *(bf16x4*)(O3l + (size_t)n * LTP + mb2) = l4;
                    } else {
#pragma unroll
                        for (int r = 0; r < 4; ++r)
                            if (mb2 + r < M) {
                                O3h[(size_t)n * LTP + mb2 + r] = h4[r];
                                O3l[(size_t)n * LTP + mb2 + r] = l4[r];
                            }
                    }
                }
            }
        } else {
            const float* bias = sel == 0 ? b0 : b1;
            __bf16* Dh = sel == 0 ? Oh : O2h;
            __bf16* Dl = sel == 0 ? Ol : O2l;
            float scale = sel == 0 ? 0.125f : 1.0f;   // fold softmax scale into Q
#pragma unroll
            for (int i = 0; i < 2; ++i)
#pragma unroll
                for (int r = 0; r < 4; ++r) {
                    int m = m0 + wm + i * 16 + q * 4 + r;
                    if (m >= M) continue;
#pragma unroll
                    for (int j = 0; j < 4; ++j) {
                        int n = c0 + j * 16 + lr;
                        float v = (acc[i][j][r] + bias[n]) * scale;
                        __bf16 hh = (__bf16)v;
                        Dh[(size_t)m * DM + n] = hh;
                        Dl[(size_t)m * DM + n] = (__bf16)(v - (float)hh);
                    }
                }
        }
        return;
    }

#pragma unroll
    for (int i = 0; i < 2; ++i)
#pragma unroll
        for (int r = 0; r < 4; ++r) {
            int m = m0 + wm + i * 16 + q * 4 + r;
            if (m >= M) continue;
            if constexpr (MODE == M_GATE1) {
                int r6 = (m < LZ) ? (m / SEQ) : 6;
                const float* g1 = params + r6 * 3072 + 2048;
                int c0 = nb * 128 + (w & 1) * 64;
#pragma unroll
                for (int j = 0; j < 4; ++j) {
                    int n = c0 + j * 16 + lr;
                    size_t o = (size_t)m * 512 + n;
                    float x = (float)Xh[o] + (float)Xl[o];
                    float v = x * g1[n] + acc[i][j][r] + b0[n];
                    __bf16 hh = (__bf16)v;
                    Oh[o] = hh;
                    Ol[o] = (__bf16)(v - (float)hh);
                }
            } else if constexpr (MODE == M_GLU) {
#pragma unroll
                for (int j = 0; j < 2; ++j) {
                    int n = nb * 64 + (w & 1) * 32 + j * 16 + lr;
                    float a = acc[i][j][r] + b0[n];
                    float g = acc[i][j + 2][r] + b0[2048 + n];
                    float gel = 0.5f * g * (1.0f + erff(g * 0.70710678118654752f));
                    float v = a * gel;
                    size_t o = (size_t)m * 2048 + n;
                    __bf16 hh = (__bf16)v;
                    Oh[o] = hh;
                    Ol[o] = (__bf16)(v - (float)hh);
                }
            } else {
                int r6 = (m < LZ) ? (m / SEQ) : 6;
                const float* g2 = params + r6 * 3072 + 2560;
                int c0 = nb * 128 + (w & 1) * 64;
#pragma unroll
                for (int j = 0; j < 4; ++j) {
                    int n = c0 + j * 16 + lr;
                    C0[(size_t)m * 512 + n] = (acc[i][j][r] + b0[n]) * g2[n];
                }
            }
        }
}

// ---- flash attention: all operands pre-split bf16 planes -------------------
// K tile staged via global_load_lds from K planes [tok][512]; V from V^T
// planes [n=h*64+d][LTP]. Tiles 64-token ABSOLUTE-aligned (16B DMA align);
// softmax masks [lo,hi). Source-XOR swizzle slot^=(row&7) + same-XOR frag
// reads -> 2-way LDS bank aliasing. Q frags direct bf16x8 loads (pre-scaled
// by 0.125 in qkv epilogue). Plane rows >= LT zeroed once by ztail.
__global__ __launch_bounds__(256) void fattn_kernel(
    const __bf16* __restrict__ Qph, const __bf16* __restrict__ Qpl,
    const __bf16* __restrict__ Kph, const __bf16* __restrict__ Kpl,
    const __bf16* __restrict__ Vph, const __bf16* __restrict__ Vpl,
    __bf16* __restrict__ Oh, __bf16* __restrict__ Ol) {
    __shared__ __align__(16) __bf16 Ksh[2][64][64];
    __shared__ __align__(16) __bf16 Vsh[2][64][64];
    __shared__ __align__(16) __bf16 Ph[4][16][72], Pl[4][16][72];
    int tid = threadIdx.x;
    int w = tid >> 6, lane = tid & 63;
    int lq = lane & 15, lg = lane >> 4;
    int hoff = blockIdx.z * DH;
    int qbase, base0, len0, base1, len1;
    if (blockIdx.y < 6) {
        int f = blockIdx.y;
        qbase = f * SEQ;
        base0 = f * SEQ; len0 = SEQ;
        int jl = f - 4; if (jl < 0) jl = 0;
        base1 = LZ + jl * SEQ; len1 = (f - jl) * SEQ;
    } else {
        int f = blockIdx.y - 6;
        qbase = LZ + f * SEQ;
        base0 = LZ; len0 = (f + 1) * SEQ;
        base1 = 0; len1 = 0;
    }
    int q0 = blockIdx.x * 64;
    int qvalid = SEQ - q0; if (qvalid > 64) qvalid = 64;

    // Q B-fragments (pre-scaled, pre-split): col q = w*16+lq, d = s*32+lg*8+j
    bf16x8 qfh[2], qfl[2];
    {
        int qr = w * 16 + lq;
        int tok = qbase + q0 + ((qr < qvalid) ? qr : 0);
        const __bf16* qph = Qph + (size_t)tok * DM + hoff + lg * 8;
        const __bf16* qpl = Qpl + (size_t)tok * DM + hoff + lg * 8;
#pragma unroll
        for (int s = 0; s < 2; ++s) {
            qfh[s] = *(const bf16x8*)(qph + s * 32);
            qfl[s] = *(const bf16x8*)(qpl + s * 32);
        }
    }
    f32x4 acc[4];
#pragma unroll
    for (int n = 0; n < 4; ++n)
#pragma unroll
        for (int r = 0; r < 4; ++r) acc[n][r] = 0.0f;
    float m_i = -1e30f, l_i = 0.0f;
    int slot = lane & 7, rsub = lane >> 3;

    for (int rng = 0; rng < 2; ++rng) {
        int base = rng ? base1 : base0;
        int len = rng ? len1 : len0;
        if (len == 0) continue;
        int tend = base + len;
        for (int t = base & ~63; t < tend; t += 64) {
            int lo = base - t; if (lo < 0) lo = 0;
            int hi = tend - t; if (hi > 64) hi = 64;
            __syncthreads();
            // ---- stage K + V^T tiles: pure global_load_lds, src-XOR swizzle
#pragma unroll
            for (int ii = 0; ii < 4; ++ii) {
                int idx = w + ii * 4;
                int p = idx >> 3, c = idx & 7;
                int row = c * 8 + rsub;
                const __bf16* g = (p ? Kpl : Kph) +
                    (size_t)(t + row) * DM + hoff + (slot ^ (row & 7)) * 8;
                __builtin_amdgcn_global_load_lds((const unsigned int*)g,
                    (unsigned int*)((char*)(&Ksh[p][0][0]) + c * 1024), 16, 0, 0);
            }
#pragma unroll
            for (int ii = 0; ii < 4; ++ii) {
                int idx = w + ii * 4;
                int p = idx >> 3, c = idx & 7;
                int d = c * 8 + rsub;
                const __bf16* g = (p ? Vpl : Vph) +
                    (size_t)(hoff + d) * LTP + t + (slot ^ (d & 7)) * 8;
                __builtin_amdgcn_global_load_lds((const unsigned int*)g,
                    (unsigned int*)((char*)(&Vsh[p][0][0]) + c * 1024), 16, 0, 0);
            }
            __syncthreads();
            // ---- S^T: 4 k-subtiles x 2 kd steps, swizzled frag reads
            f32x4 st[4];
#pragma unroll
            for (int sub = 0; sub < 4; ++sub)
#pragma unroll
                for (int r = 0; r < 4; ++r) st[sub][r] = 0.0f;
#pragma unroll
            for (int sub = 0; sub < 4; ++sub) {
                int row = sub * 16 + lq;
#pragma unroll
                for (int s = 0; s < 2; ++s) {
                    int sl = ((s * 4 + lg) ^ (row & 7)) * 8;
                    bf16x8 kfh = *(const bf16x8*)(&Ksh[0][row][sl]);
                    bf16x8 kfl = *(const bf16x8*)(&Ksh[1][row][sl]);
                    MFMA3(st[sub], kfh, kfl, qfh[s], qfl[s]);
                }
            }
            // ---- online softmax over k (fixed q = lq per lane)
            float p[16];
            float rmax = -1e30f;
#pragma unroll
            for (int sub = 0; sub < 4; ++sub)
#pragma unroll
                for (int r = 0; r < 4; ++r) {
                    int kk = sub * 16 + lg * 4 + r;
                    float sv = (kk >= lo && kk < hi) ? st[sub][r] : -1e30f;
                    p[sub * 4 + r] = sv;
                    rmax = fmaxf(rmax, sv);
                }
            rmax = fmaxf(rmax, __shfl_xor(rmax, 16));
            rmax = fmaxf(rmax, __shfl_xor(rmax, 32));
            float mnew = fmaxf(m_i, rmax);
            float alpha = __expf(m_i - mnew);
            float rsum = 0.0f;
#pragma unroll
            for (int i2 = 0; i2 < 16; ++i2) {
                p[i2] = __expf(p[i2] - mnew);
                rsum += p[i2];
            }
            rsum += __shfl_xor(rsum, 16);
            rsum += __shfl_xor(rsum, 32);
            l_i = l_i * alpha + rsum;
            m_i = mnew;
            float ar[4];
#pragma unroll
            for (int r = 0; r < 4; ++r) ar[r] = __shfl(alpha, lg * 4 + r);
#pragma unroll
            for (int n = 0; n < 4; ++n)
#pragma unroll
                for (int r = 0; r < 4; ++r) acc[n][r] *= ar[r];
            // ---- P -> wave-private LDS in PV A-layout P[q][k]
#pragma unroll
            for (int sub = 0; sub < 4; ++sub) {
                bf16x4 h4, l4;
#pragma unroll
                for (int r = 0; r < 4; ++r) {
                    float x = p[sub * 4 + r];
                    __bf16 hh = (__bf16)x;
                    h4[r] = hh;
                    l4[r] = (__bf16)(x - (float)hh);
                }
                *(bf16x4*)&Ph[w][lq][sub * 16 + lg * 4] = h4;
                *(bf16x4*)&Pl[w][lq][sub * 16 + lg * 4] = l4;
            }
            bf16x8 pah[2], pal[2];
#pragma unroll
            for (int s = 0; s < 2; ++s) {
                pah[s] = *(const bf16x8*)(&Ph[w][lq][s * 32 + lg * 8]);
                pal[s] = *(const bf16x8*)(&Pl[w][lq][s * 32 + lg * 8]);
            }
            // ---- PV: acc[n] += P @ V (V^T frags, swizzled reads)
#pragma unroll
            for (int n = 0; n < 4; ++n) {
                int row = n * 16 + lq;
#pragma unroll
                for (int s = 0; s < 2; ++s) {
                    int sl = ((s * 4 + lg) ^ (row & 7)) * 8;
                    bf16x8 vfh = *(const bf16x8*)(&Vsh[0][row][sl]);
                    bf16x8 vfl = *(const bf16x8*)(&Vsh[1][row][sl]);
                    MFMA3(acc[n], pah[s], pal[s], vfh, vfl);
                }
            }
        }
    }
    float linv[4];
#pragma unroll
    for (int r = 0; r < 4; ++r) linv[r] = 1.0f / __shfl(l_i, lg * 4 + r);
#pragma unroll
    for (int r = 0; r < 4; ++r) {
        int qr = w * 16 + lg * 4 + r;
        if (qr < qvalid) {
            size_t ob = (size_t)(qbase + q0 + qr) * DM + hoff;
#pragma unroll
            for (int n = 0; n < 4; ++n) {
                float v = acc[n][r] * linv[r];
                __bf16 hh = (__bf16)v;
                Oh[ob + n * 16 + lq] = hh;
                Ol[ob + n * 16 + lq] = (__bf16)(v - (float)hh);
            }
        }
    }
}

// ---------------- unpatch to FP32 output ------------------
__global__ void unpatch_kernel(const float* __restrict__ state,
                               const float* __restrict__ Wu,
                               const float* __restrict__ bu,
                               float* __restrict__ out) {
    int idx = blockIdx.x * blockDim.x + threadIdx.x;
    if (idx >= DURZ * 3 * 32 * 32) return;
    int w = idx & 31, hh = (idx >> 5) & 31, c = (idx >> 10) % 3, f = idx / (3 * 1024);
    int t = (hh >> 1) * 16 + (w >> 1);
    int j = c * 4 + (hh & 1) * 2 + (w & 1);
    const float* xr = state + (size_t)(f * SEQ + t) * DM;
    float acc = bu[j];
    for (int k = 0; k < DM; ++k) acc += xr[k] * Wu[k * 12 + j];
    out[idx] = acc;
}

extern "C" void kernel_launch(void* const* d_in, const int* in_sizes, int n_in,
                              void* d_out, int out_size, void* d_ws, size_t ws_size,
                              hipStream_t stream) {
    static const int expected_sizes[32] = {
        18432, 15360, 6, 6,
        6144, 512, 6144, 12,
        512, 131072, 1536, 512000,
        3145728, 6144, 3145728, 6144,
        1572864, 3072, 1572864, 3072,
        1572864, 3072, 1572864, 3072,
        1572864, 3072, 1572864, 3072,
        12582912, 24576, 6291456, 3072
    };
    if (n_in != 32) {
        fill_kernel<<<(18432 + 255) / 256, 256, 0, stream>>>((float*)d_out, 18432, 3.0f);
        return;
    }
    for (int i = 0; i < 32; ++i) {
        if (in_sizes[i] != expected_sizes[i]) {
            fill_kernel<<<(18432 + 255) / 256, 256, 0, stream>>>((float*)d_out, 18432,
                                                                 4.0f + (float)i);
            return;
        }
    }

    const float* z = (const float*)d_in[0];
    const float* frames = (const float*)d_in[1];
    const int* actions = (const int*)d_in[2];
    const int* ts = (const int*)d_in[3];
    const float* W_patch = (const float*)d_in[4];
    const float* b_patch = (const float*)d_in[5];
    const float* W_unpatch = (const float*)d_in[6];
    const float* b_unpatch = (const float*)d_in[7];
    const float* registers = (const float*)d_in[8];
    const float* pe_grid = (const float*)d_in[9];
    const float* action_emb = (const float*)d_in[10];
    const float* time_emb = (const float*)d_in[11];
    const float* W_mod1 = (const float*)d_in[12];
    const float* b_mod1 = (const float*)d_in[13];
    const float* W_mod2 = (const float*)d_in[14];
    const float* b_mod2 = (const float*)d_in[15];
    const float* W_q = (const float*)d_in[16];
    const float* b_q = (const float*)d_in[17];
    const float* W_k = (const float*)d_in[18];
    const float* b_k = (const float*)d_in[19];
    const float* W_v = (const float*)d_in[20];
    const float* b_v = (const float*)d_in[21];
    const float* W_o = (const float*)d_in[22];
    const float* b_o = (const float*)d_in[23];
    const float* W_g1 = (const float*)d_in[24];
    const float* b_g1 = (const float*)d_in[25];
    const float* W_g2 = (const float*)d_in[26];
    const float* b_g2 = (const float*)d_in[27];
    const float* W_geglu = (const float*)d_in[28];
    const float* b_geglu = (const float*)d_in[29];
    const float* W_ffout = (const float*)d_in[30];
    const float* b_ffout = (const float*)d_in[31];

    const size_t S = (size_t)LT * DM;          // 1,447,424 floats
    const size_t PLE = (size_t)LTP * DM;       // plane bf16 elems = 1,474,560
    const size_t PLF = PLE / 2;                // plane floats = 737,280
    size_t need = (4 * S + 6 * PLF + 129024 + 7168 + 5242880) * sizeof(float);
    if (ws_size < need) {
        fill_kernel<<<(18432 + 255) / 256, 256, 0, stream>>>((float*)d_out, 18432, 40.0f);
        return;
    }
    float* ws = (float*)d_ws;
    float* state = ws;                              // [0, 1S)
    __bf16* xnh = (__bf16*)(ws + S);                // [1S, 1.5S)
    __bf16* xnl = (__bf16*)(ws + S + S / 2);        // [1.5S, 2S)
    __bf16* Qh = (__bf16*)(ws + 2 * S);             // 6 planes of PLE bf16
    __bf16* Ql = Qh + PLE;
    __bf16* Kh = Qh + 2 * PLE;
    __bf16* Kl = Qh + 3 * PLE;
    __bf16* Vth = Qh + 4 * PLE;
    __bf16* Vtl = Qh + 5 * PLE;
    float* aoff = ws + 2 * S + 6 * PLF;
    __bf16* atth = (__bf16*)aoff;                   // S bf16
    __bf16* attl = atth + S;
    __bf16* y2h = (__bf16*)(aoff + S);
    __bf16* y2l = y2h + S;
    __bf16* Hph = (__bf16*)(ws + 2 * S);            // overlay (planes+att dead)
    __bf16* Hpl = Hph + (size_t)LT * HIDDEN;
    float* params = aoff + 2 * S;
    float* condraw = params + 129024;
    float* condsilu = condraw + 3584;
    float* wp = condsilu + 3584;                    // 5,242,880 floats

    embed_kernel<<<LT, 256, 0, stream>>>(z, frames, actions, W_patch, b_patch,
                                         registers, pe_grid, action_emb, state);
    cond_kernel<<<(7 * 512 + 255) / 256, 256, 0, stream>>>(ts, time_emb, condraw, condsilu);
    params_kernel<<<(6 * 7 * 3072 + 255) / 256, 256, 0, stream>>>(
        condraw, condsilu, W_mod1, b_mod1, W_mod2, b_mod2, W_g1, b_g1, W_g2, b_g2, params);
    ztail_kernel<<<((LTP - LT) * 512 + 255) / 256, 256, 0, stream>>>(Kh, Kl, Vth, Vtl);

    dim3 gqkv(45, 12);
    dim3 ggate1(45, 4);
    dim3 gglu(45, 32);
    dim3 ggate2(45, 4);
    dim3 gattn(5, 11, NHEADS);
    for (int i = 0; i < 6; ++i) {
        const float* P = params + i * 21504;
        wprep_kernel<<<2048, 256, 0, stream>>>(
            W_q + (size_t)i * DM * DM, W_k + (size_t)i * DM * DM,
            W_v + (size_t)i * DM * DM, W_o + (size_t)i * DM * DM,
            W_geglu + (size_t)i * DM * 4096, W_ffout + (size_t)i * HIDDEN * DM, wp);
        lnmod_kernel<false><<<LT, 256, 0, stream>>>(state, nullptr, nullptr,
                                                    xnh, xnl, P, 0);
        gemm_kernel<M_QKV><<<gqkv, 256, 0, stream>>>(
            xnh, xnl, (const char*)wp, 16, 512,
            b_q + i * DM, b_k + i * DM, b_v + i * DM, nullptr,
            Qh, Ql, Kh, Kl, Vth, Vtl, nullptr, nullptr, nullptr, LT);
        fattn_kernel<<<gattn, 256, 0, stream>>>(Qh, Ql, Kh, Kl, Vth, Vtl, atth, attl);
        gemm_kernel<M_GATE1><<<ggate1, 256, 0, stream>>>(
            atth, attl, (const char*)(wp + 983040), 16, 512,
            b_o + i * DM, nullptr, nullptr, nullptr,
            y2h, y2l, nullptr, nullptr, nullptr, nullptr, xnh, xnl, P, LT);
        lnmod_kernel<true><<<LT, 256, 0, stream>>>(nullptr, y2h, y2l,
                                                   xnh, xnl, P, 1024);
        gemm_kernel<M_GLU><<<gglu, 256, 0, stream>>>(
            xnh, xnl, (const char*)(wp + 1310720), 16, 512,
            b_geglu + (size_t)i * 4096, nullptr, nullptr, nullptr,
            Hph, Hpl, nullptr, nullptr, nullptr, nullptr, nullptr, nullptr, nullptr, LT);
        gemm_kernel<M_GATE2><<<ggate2, 256, 0, stream>>>(
            Hph, Hpl, (const char*)(wp + 3932160), 64, 2048,
            b_ffout + i * DM, nullptr, nullptr, state,
            nullptr, nullptr, nullptr, nullptr, nullptr, nullptr,
            nullptr, nullptr, P, LT);
    }
    unpatch_kernel<<<(DURZ * 3 * 32 * 32 + 255) / 256, 256, 0, stream>>>(
        state, W_unpatch, b_unpatch, (float*)d_out);
}